// Round 5
// baseline (738.501 us; speedup 1.0000x reference)
//
#include <hip/hip_runtime.h>

#define NN   32768
#define NV   64
#define E0E  524288
#define HID  128
#define NL   4
#define NH   8
#define DH   16
#define SCALE 0.25f
#define LDA  136   // bf16 row stride for staged A (16B-aligned frag reads, 2-way bank alias)
#define CAP0 64    // edge0 bucket capacity (multinomial ~Poisson(16), 12-sigma safe)
#define CAP1 1024  // edge1 bucket capacity (~Poisson(512), 22-sigma safe)

typedef __attribute__((ext_vector_type(8))) short short8;   // 8 bf16 = 4 VGPRs
typedef __attribute__((ext_vector_type(4))) float f32x4;

__device__ __forceinline__ float gelu_f(float x) {
  return 0.5f * x * (1.0f + erff(x * 0.7071067811865475f));
}
__device__ __forceinline__ float sigmoid_f(float x) {
  return 1.0f / (1.0f + __expf(-x));
}
__device__ __forceinline__ unsigned short f2bf(float x) {   // RN-even f32->bf16
  unsigned u = __float_as_uint(x);
  return (unsigned short)((u + 0x7FFFu + ((u >> 16) & 1u)) >> 16);
}
__device__ __forceinline__ float bf2f(unsigned short h) {
  return __uint_as_float(((unsigned)h) << 16);
}
// fp16 conversions via native _Float16 (no hip_fp16.h dependency)
__device__ __forceinline__ unsigned short f2h(float x) {
  union { _Float16 h; unsigned short u; } cv;
  cv.h = (_Float16)x;
  return cv.u;
}
__device__ __forceinline__ float h2f(unsigned short u) {
  union { _Float16 h; unsigned short u; } cv;
  cv.u = u;
  return (float)cv.h;
}
__device__ __forceinline__ float f16lo(unsigned u) { return h2f((unsigned short)(u & 0xffffu)); }
__device__ __forceinline__ float f16hi(unsigned u) { return h2f((unsigned short)(u >> 16)); }

union SMu {
  struct { unsigned short Ah[64][LDA]; unsigned short Al[64][LDA]; } a;  // 34816 B
  struct { float xr[HID]; float xn[HID]; } v;
};

// ---- stage 64xK=128 fp32 tile into split hi/lo bf16 LDS (coalesced float4 reads) ----
__device__ __forceinline__ void stage_A(unsigned short Ah[][LDA], unsigned short Al[][LDA],
                                        int t, const float* __restrict__ A, int m0, int gelu) {
  #pragma unroll
  for (int i = 0; i < 8; ++i) {
    int idx = t + 256 * i;            // float4 index over 64x32
    int m = idx >> 5, c4 = (idx & 31) * 4;
    float4 v = *(const float4*)(A + (size_t)(m0 + m) * HID + c4);
    if (gelu) { v.x = gelu_f(v.x); v.y = gelu_f(v.y); v.z = gelu_f(v.z); v.w = gelu_f(v.w); }
    unsigned short h0 = f2bf(v.x), h1 = f2bf(v.y), h2 = f2bf(v.z), h3 = f2bf(v.w);
    *(ushort4*)&Ah[m][c4] = make_ushort4(h0, h1, h2, h3);
    *(ushort4*)&Al[m][c4] = make_ushort4(f2bf(v.x - bf2f(h0)), f2bf(v.y - bf2f(h1)),
                                         f2bf(v.z - bf2f(h2)), f2bf(v.w - bf2f(h3)));
  }
}

// ---- MFMA split-bf16 single pass: 64x128 tile, K=128, B-reuse form (96 MFMAs/wave) ----
// Single-stream only (r4 lesson: dual-stream K|V held 64 acc VGPRs live -> 216 VGPR total ->
// 8 waves/CU -> all streaming ran at ~1TB/s. Sequential passes park accK at no sched cost.)
__device__ __forceinline__ void mfma_pass(const unsigned short Ah[][LDA],
    const unsigned short Al[][LDA], int t, const unsigned short* __restrict__ Wf,
    f32x4 acc[2][4]) {
  const int w = t >> 6, lane = t & 63, c16 = lane & 15, quad = lane >> 4;
  #pragma unroll
  for (int ks = 0; ks < 4; ++ks) {
    short8 ah[4], al[4];
    #pragma unroll
    for (int s = 0; s < 4; ++s) {
      ah[s] = *(const short8*)&Ah[16 * s + c16][ks * 32 + quad * 8];
      al[s] = *(const short8*)&Al[16 * s + c16][ks * 32 + quad * 8];
    }
    #pragma unroll
    for (int j = 0; j < 2; ++j) {
      const unsigned short* bp = Wf + (size_t)(((2 * w + j) * 4 + ks) * 64 + lane) * 8;
      short8 bh = *(const short8*)bp;
      short8 bl = *(const short8*)(bp + 16384);
      #pragma unroll
      for (int s = 0; s < 4; ++s) {
        acc[j][s] = __builtin_amdgcn_mfma_f32_16x16x32_bf16(ah[s], bh, acc[j][s], 0, 0, 0);
        acc[j][s] = __builtin_amdgcn_mfma_f32_16x16x32_bf16(ah[s], bl, acc[j][s], 0, 0, 0);
        acc[j][s] = __builtin_amdgcn_mfma_f32_16x16x32_bf16(al[s], bh, acc[j][s], 0, 0, 0);
      }
    }
  }
}

// ---- 3-slice projection from a staged A tile: q (fp32) + rel0 k|v + rel1 k|v (fp16 pack) ----
__device__ __forceinline__ void mproj3(const unsigned short Ah[][LDA],
    const unsigned short Al[][LDA], int t, int m0,
    const unsigned short* __restrict__ WqF, const unsigned short* __restrict__ CWF,
    const float* __restrict__ bq0, const float* __restrict__ CBl,
    float* __restrict__ Pq, unsigned int* __restrict__ Pkv0, unsigned int* __restrict__ Pkv1) {
  const int w = t >> 6, c16 = t & 15, quad = (t & 63) >> 4;
  {
    f32x4 acc[2][4] = {};
    mfma_pass(Ah, Al, t, WqF, acc);
    #pragma unroll
    for (int j = 0; j < 2; ++j) {
      const int col = (2 * w + j) * 16 + c16;
      const float bb = bq0[col];
      #pragma unroll
      for (int s = 0; s < 4; ++s)
        #pragma unroll
        for (int r = 0; r < 4; ++r) {
          int m = m0 + 16 * s + quad * 4 + r;
          Pq[(size_t)m * HID + col] = acc[j][s][r] + bb;
        }
    }
  }
  #pragma unroll
  for (int rel = 0; rel < 2; ++rel) {
    const unsigned short* WfK = CWF + (size_t)(2 * rel) * 32768;
    f32x4 accK[2][4] = {};
    mfma_pass(Ah, Al, t, WfK, accK);
    f32x4 accV[2][4] = {};
    mfma_pass(Ah, Al, t, WfK + 32768, accV);
    unsigned int* dst = rel ? Pkv1 : Pkv0;
    const float* bK = CBl + 2 * rel * HID;
    const float* bV = bK + HID;
    #pragma unroll
    for (int j = 0; j < 2; ++j) {
      const int col = (2 * w + j) * 16 + c16;
      const float bbk = bK[col], bbv = bV[col];
      #pragma unroll
      for (int s = 0; s < 4; ++s)
        #pragma unroll
        for (int r = 0; r < 4; ++r) {
          int m = m0 + 16 * s + quad * 4 + r;
          unsigned pk = (unsigned)f2h(accK[j][s][r] + bbk);
          unsigned pv = (unsigned)f2h(accV[j][s][r] + bbv);
          dst[(size_t)m * HID + col] = pk | (pv << 16);
        }
    }
  }
}

// ================= k_scatsetup: weight-combine (blocks 0-15) + bucket scatter (1 edge/thr) ====
// Scatter is atomic-latency bound: r3's 544-block/4-edge form filled ~27% of the machine
// (72us @ VALUBusy 0.1%). 1 edge/thread x 2176 blocks at ~12 VGPR = full occupancy fill.
// Combine blocks ride first in the grid (low-VGPR too -> no budget penalty, overlap free).
struct SSArgs {
  const int *src0, *dst0, *src1, *dst1;
  int *cnt0, *cnt1, *colB0, *colB1;
  const float *Wk, *Wv, *bk, *bv, *a_rel, *m_rel, *p_rel;
  float *CW, *CB;
};

__global__ __launch_bounds__(256) void k_scatsetup(SSArgs a) {
  int bx = blockIdx.x, t = threadIdx.x;
  if (bx < 16) {                             // weight-combine blk 0..15: l*4 + {K0,V0,K1,V1}
    int blk = bx;
    int l = blk >> 2, mat = blk & 3;
    int rel = mat >> 1;
    int isK = ((mat & 1) == 0);
    const float* W  = (isK ? a.Wk : a.Wv) + (size_t)(l * 2) * HID * HID;
    const float* bb = (isK ? a.bk : a.bv) + (l * 2) * HID;
    const float* R  = (isK ? a.a_rel : a.m_rel) + (size_t)((l * 2 + rel) * NH) * DH * DH;
    float* cw = a.CW + (size_t)blk * HID * HID;
    float* cb = a.CB + blk * HID;
    for (int o = t; o < HID * HID; o += 256) {
      int j = o >> 7, c = o & 127;
      int h = j >> 4, e = j & 15;
      float sc = isK ? (a.p_rel[(l * 2 + rel) * NH + h] * SCALE) : 1.0f;
      float s = 0.f;
      #pragma unroll
      for (int d = 0; d < DH; ++d)
        s += W[(size_t)(h * DH + d) * HID + c] * R[h * 256 + d * 16 + e];
      cw[(size_t)j * HID + c] = s * sc;   // [n][k]
    }
    if (t < HID) {
      int j = t, h = j >> 4, e = j & 15;
      float sc = isK ? (a.p_rel[(l * 2 + rel) * NH + h] * SCALE) : 1.0f;
      float s = 0.f;
      #pragma unroll
      for (int d = 0; d < DH; ++d) s += bb[h * DH + d] * R[h * 256 + d * 16 + e];
      cb[j] = s * sc;
    }
    return;
  }
  bx -= 16;
  if (bx < E0E / 256) {                      // edge0 bucket scatter: pos = atomic count
    int e = bx * 256 + t;
    int d = a.dst0[e];
    int pos = atomicAdd(&a.cnt0[d], 1);
    if (pos < CAP0) a.colB0[((size_t)d << 6) + pos] = a.src0[e];
    return;
  }
  bx -= E0E / 256;
  {                                          // edge1 bucket scatter
    int e = bx * 256 + t;
    int d = a.dst1[e];
    int pos = atomicAdd(&a.cnt1[d], 1);
    if (pos < CAP1) a.colB1[((size_t)d << 10) + pos] = a.src1[e];
  }
}

// ================= frag-order + split all 24 weight mats (CW 0-15, Wq0 16-19, Wa0 20-23) ======
__global__ __launch_bounds__(256) void k_frag(const float* __restrict__ CW,
                                              const float* __restrict__ Wq,
                                              const float* __restrict__ Wa,
                                              unsigned short* __restrict__ FW) {
  int m = blockIdx.x, t = threadIdx.x;
  const float* src = (m < 16) ? (CW + (size_t)m * HID * HID)
                   : (m < 20) ? (Wq + (size_t)((m - 16) * 2) * HID * HID)
                              : (Wa + (size_t)((m - 20) * 2) * HID * HID);
  unsigned short* hi = FW + (size_t)m * 32768;
  unsigned short* lo = hi + 16384;
  for (int idx = t; idx < 16384; idx += 256) {
    int j = idx & 7, lane = (idx >> 3) & 63, ks = (idx >> 9) & 3, nt = idx >> 11;
    int n = nt * 16 + (lane & 15);
    int k = ks * 32 + (lane >> 4) * 8 + j;
    float x = src[(size_t)n * HID + k];
    unsigned short h = f2bf(x);
    hi[idx] = h;
    lo[idx] = f2bf(x - bf2f(h));
  }
}

// ================= k_mproj0: layer-0 projection (blocks < 512) + qv0 (blocks 512..575) ========
__global__ __launch_bounds__(256, 3) void k_mproj0(
    const float* __restrict__ x_op, const unsigned short* __restrict__ FW,
    const float* __restrict__ bq, const float* __restrict__ CB,
    float* __restrict__ Pq, unsigned int* __restrict__ Pkv0, unsigned int* __restrict__ Pkv1,
    const float* __restrict__ x_v, const float* __restrict__ Wq1,
    const float* __restrict__ bq1, float* __restrict__ qv) {
  __shared__ SMu sm;
  const int t = threadIdx.x;
  if (blockIdx.x < NN / 64) {
    int m0 = blockIdx.x * 64;
    stage_A(sm.a.Ah, sm.a.Al, t, x_op, m0, 0);
    __syncthreads();
    mproj3(sm.a.Ah, sm.a.Al, t, m0, FW + (size_t)16 * 32768, FW, bq, CB, Pq, Pkv0, Pkv1);
    return;
  }
  int v = blockIdx.x - NN / 64;              // qv0 for vnode v
  if (t < HID) sm.v.xr[t] = x_v[v * HID + t];
  __syncthreads();
  if (t < HID) {
    float s = bq1[t];
    const float4* wr = (const float4*)(Wq1 + (size_t)t * HID);
    const float4* xx = (const float4*)sm.v.xr;
    #pragma unroll 8
    for (int c = 0; c < HID / 4; ++c) {
      float4 w4 = wr[c], x4 = xx[c];
      s += x4.x * w4.x + x4.y * w4.y + x4.z * w4.z + x4.w * w4.w;
    }
    qv[v * HID + t] = s;
  }
}

// ================= k_edges: edge0 (blocks < NN/4) + edge1 (NN/4 .. +512), bucket CSR ==========
__launch_bounds__(256)
__global__ void k_edges(const float* __restrict__ Pq, const unsigned int* __restrict__ Pkv0,
                        const unsigned int* __restrict__ Pkv1,
                        const int* __restrict__ cnt0, const int* __restrict__ colB0,
                        float* __restrict__ agg, const float* __restrict__ qv,
                        const int* __restrict__ cnt1, const int* __restrict__ colB1,
                        float* __restrict__ part) {
  int lane = threadIdx.x & 63;
  if (blockIdx.x < NN / 4) {
    int n = blockIdx.x * 4 + (threadIdx.x >> 6);
    float2 q = *(const float2*)(Pq + (size_t)n * HID + 2 * lane);
    int cnt = cnt0[n]; if (cnt > CAP0) cnt = CAP0;
    int e = n << 6, e1 = (n << 6) + cnt;
    float acc0 = 0.f, acc1 = 0.f, wsum = 0.f;
    for (; e + 8 <= e1; e += 8) {
      const uint2* r[8];
      #pragma unroll
      for (int u = 0; u < 8; ++u)
        r[u] = (const uint2*)(Pkv0 + ((size_t)colB0[e + u] << 7) + 2 * lane);
      uint2 kv[8];
      #pragma unroll
      for (int u = 0; u < 8; ++u) kv[u] = *r[u];
      float p[8];
      #pragma unroll
      for (int u = 0; u < 8; ++u)
        p[u] = q.x * f16lo(kv[u].x) + q.y * f16lo(kv[u].y);
      #pragma unroll
      for (int u = 0; u < 8; ++u) {
        p[u] += __shfl_xor(p[u], 1); p[u] += __shfl_xor(p[u], 2); p[u] += __shfl_xor(p[u], 4);
      }
      #pragma unroll
      for (int u = 0; u < 8; ++u) {
        float wg = __expf(p[u]);
        wsum += wg; acc0 += wg * f16hi(kv[u].x); acc1 += wg * f16hi(kv[u].y);
      }
    }
    for (; e < e1; ++e) {
      uint2 kv = *(const uint2*)(Pkv0 + ((size_t)colB0[e] << 7) + 2 * lane);
      float p = q.x * f16lo(kv.x) + q.y * f16lo(kv.y);
      p += __shfl_xor(p, 1); p += __shfl_xor(p, 2); p += __shfl_xor(p, 4);
      float wg = __expf(p);
      wsum += wg; acc0 += wg * f16hi(kv.x); acc1 += wg * f16hi(kv.y);
    }
    float inv = 1.0f / (wsum + 1e-16f);
    *(float2*)(agg + (size_t)n * HID + 2 * lane) = make_float2(acc0 * inv, acc1 * inv);
  } else {
    int b2 = blockIdx.x - NN / 4;
    int g = b2 >> 3, ch = b2 & 7;
    int w = threadIdx.x >> 6;
    int slot = ch * 4 + w;
    float2 q = *(const float2*)(qv + g * HID + 2 * lane);
    int tot = cnt1[g]; if (tot > CAP1) tot = CAP1;
    int base = g << 10;
    int len = (tot + 31) >> 5;
    int s0 = base + slot * len;
    int s1 = s0 + len; int lim = base + tot; if (s1 > lim) s1 = lim;
    float acc0 = 0.f, acc1 = 0.f, wsum = 0.f;
    int e = s0;
    for (; e + 4 <= s1; e += 4) {
      uint2 ka = *(const uint2*)(Pkv1 + ((size_t)colB1[e]     << 7) + 2 * lane);
      uint2 kb = *(const uint2*)(Pkv1 + ((size_t)colB1[e + 1] << 7) + 2 * lane);
      uint2 kc = *(const uint2*)(Pkv1 + ((size_t)colB1[e + 2] << 7) + 2 * lane);
      uint2 kd = *(const uint2*)(Pkv1 + ((size_t)colB1[e + 3] << 7) + 2 * lane);
      float pa = q.x * f16lo(ka.x) + q.y * f16lo(ka.y);
      float pb = q.x * f16lo(kb.x) + q.y * f16lo(kb.y);
      float pc = q.x * f16lo(kc.x) + q.y * f16lo(kc.y);
      float pd = q.x * f16lo(kd.x) + q.y * f16lo(kd.y);
      pa += __shfl_xor(pa, 1); pb += __shfl_xor(pb, 1); pc += __shfl_xor(pc, 1); pd += __shfl_xor(pd, 1);
      pa += __shfl_xor(pa, 2); pb += __shfl_xor(pb, 2); pc += __shfl_xor(pc, 2); pd += __shfl_xor(pd, 2);
      pa += __shfl_xor(pa, 4); pb += __shfl_xor(pb, 4); pc += __shfl_xor(pc, 4); pd += __shfl_xor(pd, 4);
      float wa = __expf(pa), wb = __expf(pb), wc = __expf(pc), wd = __expf(pd);
      wsum += (wa + wb) + (wc + wd);
      acc0 += wa * f16hi(ka.x) + wb * f16hi(kb.x) + wc * f16hi(kc.x) + wd * f16hi(kd.x);
      acc1 += wa * f16hi(ka.y) + wb * f16hi(kb.y) + wc * f16hi(kc.y) + wd * f16hi(kd.y);
    }
    for (; e < s1; ++e) {
      uint2 kv = *(const uint2*)(Pkv1 + ((size_t)colB1[e] << 7) + 2 * lane);
      float p = q.x * f16lo(kv.x) + q.y * f16lo(kv.y);
      p += __shfl_xor(p, 1); p += __shfl_xor(p, 2); p += __shfl_xor(p, 4);
      float ww = __expf(p);
      wsum += ww; acc0 += ww * f16hi(kv.x); acc1 += ww * f16hi(kv.y);
    }
    float* pp = part + (size_t)(g * 32 + slot) * 192;
    pp[lane] = acc0; pp[64 + lane] = acc1; pp[128 + lane] = wsum;
  }
}

// ================= k_post: out-GEMM + skip, then next-layer projection from the live tile =====
struct PArgs {
  const float *agg; const unsigned short *WaF_l; const float *ba_l0, *skip_l0, *xold;
  float *xop;
  const float *part, *Wa_l1, *ba_l1, *skip_l1, *xvold;
  float *xv, *outsv_l, *qv;
  const float *Wq_n1, *bq_n1;
  int do_qv;
  const unsigned short *WqF_n, *CWF_n;   // next-layer frag weights
  const float *bq_n0, *CB_n;
  float *Pq; unsigned int *Pkv0, *Pkv1;
  int do_proj;
};

__launch_bounds__(256, 3)
__global__ void k_post(PArgs f) {
  __shared__ SMu sm;
  const int t = threadIdx.x;
  if (blockIdx.x >= NN / 64) {
    // ---- vnode tail: edge1red + gelu + Wa[l,1] + skip -> xv, outsv; then qv(l+1) ----
    int v = blockIdx.x - NN / 64;
    if (t < 64) {
      float a0 = 0.f, a1 = 0.f, ws2 = 0.f;
      for (int s = 0; s < 32; ++s) {
        const float* p = f.part + (size_t)(v * 32 + s) * 192;
        a0 += p[t]; a1 += p[64 + t]; ws2 += p[128 + t];
      }
      float inv = 1.0f / (ws2 + 1e-16f);
      sm.v.xr[2 * t]     = gelu_f(a0 * inv);
      sm.v.xr[2 * t + 1] = gelu_f(a1 * inv);
    }
    __syncthreads();
    if (t < HID) {
      float s = f.ba_l1[t];
      const float4* wr = (const float4*)(f.Wa_l1 + (size_t)t * HID);
      const float4* xx = (const float4*)sm.v.xr;
      #pragma unroll 8
      for (int c = 0; c < HID / 4; ++c) {
        float4 w4 = wr[c], x4 = xx[c];
        s += x4.x * w4.x + x4.y * w4.y + x4.z * w4.z + x4.w * w4.w;
      }
      float gg = sigmoid_f(*f.skip_l1);
      float nv2 = gg * s + (1.f - gg) * f.xvold[v * HID + t];
      f.xv[v * HID + t] = nv2;
      f.outsv_l[v * HID + t] = nv2;
      sm.v.xn[t] = nv2;
    }
    __syncthreads();
    if (f.do_qv && t < HID) {
      float s = f.bq_n1[t];
      const float4* wr = (const float4*)(f.Wq_n1 + (size_t)t * HID);
      const float4* xx = (const float4*)sm.v.xn;
      #pragma unroll 8
      for (int c = 0; c < HID / 4; ++c) {
        float4 w4 = wr[c], x4 = xx[c];
        s += x4.x * w4.x + x4.y * w4.y + x4.z * w4.z + x4.w * w4.w;
      }
      f.qv[v * HID + t] = s;
    }
    return;
  }
  const int m0 = blockIdx.x * 64;
  // post(l): xop = g*(gelu(agg)@Wa^T + ba) + (1-g)*xold
  stage_A(sm.a.Ah, sm.a.Al, t, f.agg, m0, 1);
  __syncthreads();
  f32x4 acc[2][4] = {};
  mfma_pass(sm.a.Ah, sm.a.Al, t, f.WaF_l, acc);
  const int w = t >> 6, c16 = t & 15, quad = (t & 63) >> 4;
  float g = sigmoid_f(*f.skip_l0), gm1 = 1.0f - g;
  #pragma unroll
  for (int j = 0; j < 2; ++j) {
    const int col = (2 * w + j) * 16 + c16;
    const float bb = f.ba_l0[col];
    #pragma unroll
    for (int s = 0; s < 4; ++s)
      #pragma unroll
      for (int r = 0; r < 4; ++r) {
        int lm = 16 * s + quad * 4 + r;
        float v = acc[j][s][r] + bb;
        v = g * v + gm1 * f.xold[(size_t)(m0 + lm) * HID + col];
        acc[j][s][r] = v;                         // keep for re-stage
        f.xop[(size_t)(m0 + lm) * HID + col] = v;
      }
  }
  if (!f.do_proj) return;                         // uniform across grid: all op-blocks agree
  __syncthreads();                                // all waves done reading old A tile
  #pragma unroll
  for (int j = 0; j < 2; ++j) {
    const int col = (2 * w + j) * 16 + c16;
    #pragma unroll
    for (int s = 0; s < 4; ++s)
      #pragma unroll
      for (int r = 0; r < 4; ++r) {
        int lm = 16 * s + quad * 4 + r;
        float v = acc[j][s][r];
        unsigned short h = f2bf(v);
        sm.a.Ah[lm][col] = h;
        sm.a.Al[lm][col] = f2bf(v - bf2f(h));
      }
  }
  __syncthreads();
  mproj3(sm.a.Ah, sm.a.Al, t, m0, f.WqF_n, f.CWF_n, f.bq_n0, f.CB_n, f.Pq, f.Pkv0, f.Pkv1);
}

// ================= JK attention + node/graph MLPs =============================================
struct TailW {
  const float *win, *bin, *wout, *bout;
  const float *nw0, *nb0, *nw1, *nb1, *nw2, *nb2, *nw3, *nb3, *nw4, *nb4, *nw5, *nb5, *nw6, *nb6;
  const float *gw0, *gb0, *gw1, *gb1;
};

__launch_bounds__(128)
__global__ void k_final(const float* __restrict__ outsv, TailW tw, float* __restrict__ outp) {
  __shared__ float xs[4][HID], qq[4][HID], kk[4][HID], vv[4][HID], oo[4][HID];
  __shared__ float att[NH][4][4];
  __shared__ float hb[HID], tb[64];
  int b = blockIdx.x, t = threadIdx.x;
  for (int l = 0; l < 4; ++l) xs[l][t] = outsv[(size_t)(l * NV + b) * HID + t];
  __syncthreads();
  for (int l = 0; l < 4; ++l) {
    float sq = tw.bin[t], sk = tw.bin[t + 128], sv = tw.bin[t + 256];
    const float* wq = tw.win + (size_t)t * HID;
    const float* wk = tw.win + (size_t)(t + 128) * HID;
    const float* wv = tw.win + (size_t)(t + 256) * HID;
    for (int c = 0; c < HID; ++c) {
      float x = xs[l][c];
      sq += x * wq[c]; sk += x * wk[c]; sv += x * wv[c];
    }
    qq[l][t] = sq; kk[l][t] = sk; vv[l][t] = sv;
  }
  __syncthreads();
  {
    int h = t >> 4, ql = (t >> 2) & 3, kl = t & 3;
    float s = 0.f;
    #pragma unroll
    for (int d = 0; d < DH; ++d) s += qq[ql][h * DH + d] * kk[kl][h * DH + d];
    att[h][ql][kl] = s * SCALE;
  }
  __syncthreads();
  if (t < 32) {
    int h = t >> 2, ql = t & 3;
    float m = att[h][ql][0];
    for (int k2 = 1; k2 < 4; ++k2) m = fmaxf(m, att[h][ql][k2]);
    float e[4], s = 0.f;
    for (int k2 = 0; k2 < 4; ++k2) { e[k2] = __expf(att[h][ql][k2] - m); s += e[k2]; }
    for (int k2 = 0; k2 < 4; ++k2) att[h][ql][k2] = e[k2] / s;
  }
  __syncthreads();
  {
    int h = t >> 4;
    #pragma unroll
    for (int ql = 0; ql < 4; ++ql) {
      float s = 0.f;
      #pragma unroll
      for (int kl = 0; kl < 4; ++kl) s += att[h][ql][kl] * vv[kl][t];
      oo[ql][t] = s;
    }
  }
  __syncthreads();
  {
    float s = 0.f;
    const float* wr = tw.wout + (size_t)t * HID;
    for (int l = 0; l < 4; ++l) {
      float ss = tw.bout[t];
      for (int c = 0; c < HID; ++c) ss += oo[l][c] * wr[c];
      s += ss;
    }
    hb[t] = s;
  }
  __syncthreads();
  if (t < 64) { float s = tw.nb0[t]; const float* wr = tw.nw0 + t * 128; for (int c = 0; c < 128; ++c) s += hb[c] * wr[c]; tb[t] = gelu_f(s); }
  __syncthreads();
  if (t < 32) { float s = tw.nb1[t]; const float* wr = tw.nw1 + t * 64;  for (int c = 0; c < 64;  ++c) s += tb[c] * wr[c]; hb[t] = gelu_f(s); }
  __syncthreads();
  if (t < 16) { float s = tw.nb2[t]; const float* wr = tw.nw2 + t * 32;  for (int c = 0; c < 32;  ++c) s += hb[c] * wr[c]; tb[t] = gelu_f(s); }
  __syncthreads();
  if (t < 8)  { float s = tw.nb3[t]; const float* wr = tw.nw3 + t * 16;  for (int c = 0; c < 16;  ++c) s += tb[c] * wr[c]; hb[t] = gelu_f(s); }
  __syncthreads();
  if (t < 4)  { float s = tw.nb4[t]; const float* wr = tw.nw4 + t * 8;   for (int c = 0; c < 8;   ++c) s += hb[c] * wr[c]; tb[t] = gelu_f(s); }
  __syncthreads();
  if (t < 2)  { float s = tw.nb5[t]; const float* wr = tw.nw5 + t * 4;   for (int c = 0; c < 4;   ++c) s += tb[c] * wr[c]; hb[t] = gelu_f(s); }
  __syncthreads();
  if (t == 0) {
    float s = hb[0] * tw.nw6[0] + hb[1] * tw.nw6[1] + tw.nb6[0];
    float g0 = gelu_f(s * tw.gw0[0] + tw.gb0[0]);
    float g1 = gelu_f(s * tw.gw0[1] + tw.gb0[1]);
    outp[b] = g0 * tw.gw1[0] + g1 * tw.gw1[1] + tw.gb1[0];
  }
}

// ================= host =======================================================================
extern "C" void kernel_launch(void* const* d_in, const int* in_sizes, int n_in,
                              void* d_out, int out_size, void* d_ws, size_t ws_size,
                              hipStream_t stream) {
  const float* x_op = (const float*)d_in[0];
  const float* x_v  = (const float*)d_in[1];
  const int*   ei0  = (const int*)d_in[2];
  const int*   ei1  = (const int*)d_in[3];
  const float* Wk   = (const float*)d_in[4];
  const float* Wq   = (const float*)d_in[5];
  const float* Wv   = (const float*)d_in[6];
  const float* Wa   = (const float*)d_in[7];
  const float* bk   = (const float*)d_in[8];
  const float* bq   = (const float*)d_in[9];
  const float* bv   = (const float*)d_in[10];
  const float* ba   = (const float*)d_in[11];
  const float* skip = (const float*)d_in[12];
  const float* a_rel = (const float*)d_in[13];
  const float* m_rel = (const float*)d_in[14];
  const float* p_rel = (const float*)d_in[15];
  (void)in_sizes; (void)n_in; (void)out_size; (void)ws_size;

  char* wsp = (char*)d_ws;
  size_t off = 0;
  auto alloc = [&](size_t bytes) -> void* {
    void* p = wsp + off;
    off += (bytes + 255) & ~(size_t)255;
    return p;
  };
  float* Pq    = (float*)alloc((size_t)NN * HID * 4);
  unsigned int* Pkv0 = (unsigned int*)alloc((size_t)NN * HID * 4);  // fp16 k|v packed per dword
  unsigned int* Pkv1 = (unsigned int*)alloc((size_t)NN * HID * 4);
  float* xop   = (float*)alloc((size_t)NN * HID * 4);
  float* agg   = (float*)alloc((size_t)NN * HID * 4);
  float* CW    = (float*)alloc((size_t)16 * HID * HID * 4);
  float* CB    = (float*)alloc((size_t)16 * HID * 4);
  unsigned short* FW = (unsigned short*)alloc((size_t)24 * 32768 * 2);  // 1.57 MB frag weights
  float* xv    = (float*)alloc((size_t)NV * HID * 4);
  float* qv    = (float*)alloc((size_t)NV * HID * 4);
  float* outsv = (float*)alloc((size_t)NL * NV * HID * 4);
  float* part  = (float*)alloc((size_t)NV * 32 * 192 * 4);
  int* cnt0    = (int*)alloc((size_t)NN * 4);
  int* colB0   = (int*)alloc((size_t)NN * CAP0 * 4);   // 8 MB fixed-cap buckets
  int* cnt1    = (int*)alloc((size_t)NV * 4);
  int* colB1   = (int*)alloc((size_t)NV * CAP1 * 4);

  hipMemsetAsync(cnt0, 0, (size_t)NN * 4, stream);
  hipMemsetAsync(cnt1, 0, (size_t)NV * 4, stream);

  SSArgs sa;
  sa.src0 = ei0; sa.dst0 = ei0 + E0E;
  sa.src1 = ei1; sa.dst1 = ei1 + NN;
  sa.cnt0 = cnt0; sa.cnt1 = cnt1; sa.colB0 = colB0; sa.colB1 = colB1;
  sa.Wk = Wk; sa.Wv = Wv; sa.bk = bk; sa.bv = bv;
  sa.a_rel = a_rel; sa.m_rel = m_rel; sa.p_rel = p_rel;
  sa.CW = CW; sa.CB = CB;
  k_scatsetup<<<16 + E0E / 256 + NN / 256, 256, 0, stream>>>(sa);

  k_frag<<<24, 256, 0, stream>>>(CW, Wq, Wa, FW);
  k_mproj0<<<NN / 64 + NV, 256, 0, stream>>>(x_op, FW, bq, CB, Pq, Pkv0, Pkv1,
                                             x_v, Wq + (size_t)1 * HID * HID, bq + HID, qv);

  for (int l = 0; l < NL; ++l) {
    k_edges<<<NN / 4 + NV * 8, 256, 0, stream>>>(Pq, Pkv0, Pkv1, cnt0, colB0, agg,
                                                 qv, cnt1, colB1, part);
    PArgs f;
    f.agg = agg;
    f.WaF_l = FW + (size_t)(20 + l) * 32768;
    f.ba_l0 = ba + (l * 2 + 0) * HID;
    f.skip_l0 = skip + l * 2 + 0;
    f.xold = (l == 0) ? x_op : xop;
    f.xop = xop;
    f.part = part;
    f.Wa_l1 = Wa + (size_t)(l * 2 + 1) * HID * HID;
    f.ba_l1 = ba + (l * 2 + 1) * HID;
    f.skip_l1 = skip + l * 2 + 1;
    f.xvold = (l == 0) ? x_v : xv;
    f.xv = xv;
    f.outsv_l = outsv + (size_t)l * NV * HID;
    f.qv = qv;
    int ln = (l + 1) & 3;
    f.Wq_n1 = Wq + (size_t)(ln * 2 + 1) * HID * HID;
    f.bq_n1 = bq + (ln * 2 + 1) * HID;
    f.do_qv = (l < NL - 1) ? 1 : 0;
    f.WqF_n = FW + (size_t)(16 + ln) * 32768;
    f.CWF_n = FW + (size_t)(ln * 4) * 32768;
    f.bq_n0 = bq + (ln * 2 + 0) * HID;
    f.CB_n  = CB + ln * 4 * HID;
    f.Pq = Pq; f.Pkv0 = Pkv0; f.Pkv1 = Pkv1;
    f.do_proj = (l < NL - 1) ? 1 : 0;
    k_post<<<NN / 64 + NV, 256, 0, stream>>>(f);
  }

  TailW tw;
  tw.win  = (const float*)d_in[16]; tw.bin  = (const float*)d_in[17];
  tw.wout = (const float*)d_in[18]; tw.bout = (const float*)d_in[19];
  tw.nw0 = (const float*)d_in[20]; tw.nb0 = (const float*)d_in[21];
  tw.nw1 = (const float*)d_in[22]; tw.nb1 = (const float*)d_in[23];
  tw.nw2 = (const float*)d_in[24]; tw.nb2 = (const float*)d_in[25];
  tw.nw3 = (const float*)d_in[26]; tw.nb3 = (const float*)d_in[27];
  tw.nw4 = (const float*)d_in[28]; tw.nb4 = (const float*)d_in[29];
  tw.nw5 = (const float*)d_in[30]; tw.nb5 = (const float*)d_in[31];
  tw.nw6 = (const float*)d_in[32]; tw.nb6 = (const float*)d_in[33];
  tw.gw0 = (const float*)d_in[34]; tw.gb0 = (const float*)d_in[35];
  tw.gw1 = (const float*)d_in[36]; tw.gb1 = (const float*)d_in[37];
  k_final<<<NV, 128, 0, stream>>>(outsv, tw, (float*)d_out);
}

// Round 6
// 712.683 us; speedup vs baseline: 1.0362x; 1.0362x over previous
//
#include <hip/hip_runtime.h>

#define NN   32768
#define NV   64
#define E0E  524288
#define HID  128
#define NL   4
#define NH   8
#define DH   16
#define SCALE 0.25f
#define LDA  136   // bf16 row stride for staged A (16B-aligned frag reads, 2-way bank alias)
#define CAP0 64    // edge0 bucket capacity (multinomial ~Poisson(16), 12-sigma safe)
#define CAP1 1024  // edge1 bucket capacity (~Poisson(512), 22-sigma safe)

typedef __attribute__((ext_vector_type(8))) short short8;   // 8 bf16 = 4 VGPRs
typedef __attribute__((ext_vector_type(4))) float f32x4;

__device__ __forceinline__ float gelu_f(float x) {
  return 0.5f * x * (1.0f + erff(x * 0.7071067811865475f));
}
__device__ __forceinline__ float sigmoid_f(float x) {
  return 1.0f / (1.0f + __expf(-x));
}
__device__ __forceinline__ unsigned short f2bf(float x) {   // RN-even f32->bf16
  unsigned u = __float_as_uint(x);
  return (unsigned short)((u + 0x7FFFu + ((u >> 16) & 1u)) >> 16);
}
__device__ __forceinline__ float bf2f(unsigned short h) {
  return __uint_as_float(((unsigned)h) << 16);
}
// fp16 conversions via native _Float16 (no hip_fp16.h dependency)
__device__ __forceinline__ unsigned short f2h(float x) {
  union { _Float16 h; unsigned short u; } cv;
  cv.h = (_Float16)x;
  return cv.u;
}
__device__ __forceinline__ float h2f(unsigned short u) {
  union { _Float16 h; unsigned short u; } cv;
  cv.u = u;
  return (float)cv.h;
}
__device__ __forceinline__ float f16lo(unsigned u) { return h2f((unsigned short)(u & 0xffffu)); }
__device__ __forceinline__ float f16hi(unsigned u) { return h2f((unsigned short)(u >> 16)); }

union SMu {
  struct { unsigned short Ah[64][LDA]; unsigned short Al[64][LDA]; } a;  // 34816 B
  struct { float xr[HID]; float xn[HID]; } v;
};

// ---- stage 64xK=128 fp32 tile into split hi/lo bf16 LDS (coalesced float4 reads) ----
__device__ __forceinline__ void stage_A(unsigned short Ah[][LDA], unsigned short Al[][LDA],
                                        int t, const float* __restrict__ A, int m0, int gelu) {
  #pragma unroll
  for (int i = 0; i < 8; ++i) {
    int idx = t + 256 * i;            // float4 index over 64x32
    int m = idx >> 5, c4 = (idx & 31) * 4;
    float4 v = *(const float4*)(A + (size_t)(m0 + m) * HID + c4);
    if (gelu) { v.x = gelu_f(v.x); v.y = gelu_f(v.y); v.z = gelu_f(v.z); v.w = gelu_f(v.w); }
    unsigned short h0 = f2bf(v.x), h1 = f2bf(v.y), h2 = f2bf(v.z), h3 = f2bf(v.w);
    *(ushort4*)&Ah[m][c4] = make_ushort4(h0, h1, h2, h3);
    *(ushort4*)&Al[m][c4] = make_ushort4(f2bf(v.x - bf2f(h0)), f2bf(v.y - bf2f(h1)),
                                         f2bf(v.z - bf2f(h2)), f2bf(v.w - bf2f(h3)));
  }
}

// ---- MFMA split-bf16 single pass: 64x128 tile, K=128, B-reuse form (96 MFMAs/wave) ----
// Single-stream (r4 lesson: dual K|V stream -> 216 VGPR -> 2 blk/CU -> streaming starved).
// NO launch_bounds min-wave cap (r5 lesson: (256,3) forced VGPR 84 -> scratch spill, 139us).
__device__ __forceinline__ void mfma_pass(const unsigned short Ah[][LDA],
    const unsigned short Al[][LDA], int t, const unsigned short* __restrict__ Wf,
    f32x4 acc[2][4]) {
  const int w = t >> 6, lane = t & 63, c16 = lane & 15, quad = lane >> 4;
  #pragma unroll
  for (int ks = 0; ks < 4; ++ks) {
    short8 ah[4], al[4];
    #pragma unroll
    for (int s = 0; s < 4; ++s) {
      ah[s] = *(const short8*)&Ah[16 * s + c16][ks * 32 + quad * 8];
      al[s] = *(const short8*)&Al[16 * s + c16][ks * 32 + quad * 8];
    }
    #pragma unroll
    for (int j = 0; j < 2; ++j) {
      const unsigned short* bp = Wf + (size_t)(((2 * w + j) * 4 + ks) * 64 + lane) * 8;
      short8 bh = *(const short8*)bp;
      short8 bl = *(const short8*)(bp + 16384);
      #pragma unroll
      for (int s = 0; s < 4; ++s) {
        acc[j][s] = __builtin_amdgcn_mfma_f32_16x16x32_bf16(ah[s], bh, acc[j][s], 0, 0, 0);
        acc[j][s] = __builtin_amdgcn_mfma_f32_16x16x32_bf16(ah[s], bl, acc[j][s], 0, 0, 0);
        acc[j][s] = __builtin_amdgcn_mfma_f32_16x16x32_bf16(al[s], bh, acc[j][s], 0, 0, 0);
      }
    }
  }
}

// ---- 3-slice projection from a staged A tile: q (fp32) + rel0 k|v + rel1 k|v (fp16 pack) ----
// K results packed to 16 u32s (fp16 pairs) before the V pass: only 16 VGPR carried across,
// peak pressure ~A(32)+accV(32)+kp(16) ~ fits 4 waves/SIMD.
__device__ __forceinline__ void mproj3(const unsigned short Ah[][LDA],
    const unsigned short Al[][LDA], int t, int m0,
    const unsigned short* __restrict__ WqF, const unsigned short* __restrict__ CWF,
    const float* __restrict__ bq0, const float* __restrict__ CBl,
    float* __restrict__ Pq, unsigned int* __restrict__ Pkv0, unsigned int* __restrict__ Pkv1) {
  const int w = t >> 6, c16 = t & 15, quad = (t & 63) >> 4;
  {
    f32x4 acc[2][4] = {};
    mfma_pass(Ah, Al, t, WqF, acc);
    #pragma unroll
    for (int j = 0; j < 2; ++j) {
      const int col = (2 * w + j) * 16 + c16;
      const float bb = bq0[col];
      #pragma unroll
      for (int s = 0; s < 4; ++s)
        #pragma unroll
        for (int r = 0; r < 4; ++r) {
          int m = m0 + 16 * s + quad * 4 + r;
          Pq[(size_t)m * HID + col] = acc[j][s][r] + bb;
        }
    }
  }
  #pragma unroll
  for (int rel = 0; rel < 2; ++rel) {
    const unsigned short* WfK = CWF + (size_t)(2 * rel) * 32768;
    unsigned kp[2][4][2];
    {
      f32x4 accK[2][4] = {};
      mfma_pass(Ah, Al, t, WfK, accK);
      const float* bK = CBl + 2 * rel * HID;
      #pragma unroll
      for (int j = 0; j < 2; ++j) {
        const float bbk = bK[(2 * w + j) * 16 + c16];
        #pragma unroll
        for (int s = 0; s < 4; ++s)
          #pragma unroll
          for (int rr = 0; rr < 2; ++rr)
            kp[j][s][rr] = (unsigned)f2h(accK[j][s][2 * rr] + bbk)
                         | ((unsigned)f2h(accK[j][s][2 * rr + 1] + bbk) << 16);
      }
    }
    {
      f32x4 accV[2][4] = {};
      mfma_pass(Ah, Al, t, WfK + 32768, accV);
      unsigned int* dst = rel ? Pkv1 : Pkv0;
      const float* bV = CBl + (2 * rel + 1) * HID;
      #pragma unroll
      for (int j = 0; j < 2; ++j) {
        const int col = (2 * w + j) * 16 + c16;
        const float bbv = bV[col];
        #pragma unroll
        for (int s = 0; s < 4; ++s)
          #pragma unroll
          for (int r = 0; r < 4; ++r) {
            int m = m0 + 16 * s + quad * 4 + r;
            unsigned pk = (kp[j][s][r >> 1] >> ((r & 1) * 16)) & 0xffffu;
            unsigned pv = (unsigned)f2h(accV[j][s][r] + bbv);
            dst[(size_t)m * HID + col] = pk | (pv << 16);
          }
      }
    }
  }
}

// ================= k_setup: weight-combine only (16 blocks; cnt zeroing via memset) ===========
__global__ __launch_bounds__(256) void k_setup(
    const float* __restrict__ Wk, const float* __restrict__ Wv,
    const float* __restrict__ bk, const float* __restrict__ bv,
    const float* __restrict__ a_rel, const float* __restrict__ m_rel,
    const float* __restrict__ p_rel,
    float* __restrict__ CW, float* __restrict__ CB) {
  int blk = blockIdx.x, t = threadIdx.x;   // 0..15: l*4 + {K0,V0,K1,V1}
  int l = blk >> 2, mat = blk & 3;
  int rel = mat >> 1;
  int isK = ((mat & 1) == 0);
  const float* W  = (isK ? Wk : Wv) + (size_t)(l * 2) * HID * HID;
  const float* bb = (isK ? bk : bv) + (l * 2) * HID;
  const float* R  = (isK ? a_rel : m_rel) + (size_t)((l * 2 + rel) * NH) * DH * DH;
  float* cw = CW + (size_t)blk * HID * HID;
  float* cb = CB + blk * HID;
  for (int o = t; o < HID * HID; o += 256) {
    int j = o >> 7, c = o & 127;
    int h = j >> 4, e = j & 15;
    float sc = isK ? (p_rel[(l * 2 + rel) * NH + h] * SCALE) : 1.0f;
    float s = 0.f;
    #pragma unroll
    for (int d = 0; d < DH; ++d)
      s += W[(size_t)(h * DH + d) * HID + c] * R[h * 256 + d * 16 + e];
    cw[(size_t)j * HID + c] = s * sc;   // [n][k]
  }
  if (t < HID) {
    int j = t, h = j >> 4, e = j & 15;
    float sc = isK ? (p_rel[(l * 2 + rel) * NH + h] * SCALE) : 1.0f;
    float s = 0.f;
    #pragma unroll
    for (int d = 0; d < DH; ++d) s += bb[h * DH + d] * R[h * 256 + d * 16 + e];
    cb[j] = s * sc;
  }
}

// ================= frag-order + split all 24 weight mats (CW 0-15, Wq0 16-19, Wa0 20-23) ======
__global__ __launch_bounds__(256) void k_frag(const float* __restrict__ CW,
                                              const float* __restrict__ Wq,
                                              const float* __restrict__ Wa,
                                              unsigned short* __restrict__ FW) {
  int m = blockIdx.x, t = threadIdx.x;
  const float* src = (m < 16) ? (CW + (size_t)m * HID * HID)
                   : (m < 20) ? (Wq + (size_t)((m - 16) * 2) * HID * HID)
                              : (Wa + (size_t)((m - 20) * 2) * HID * HID);
  unsigned short* hi = FW + (size_t)m * 32768;
  unsigned short* lo = hi + 16384;
  for (int idx = t; idx < 16384; idx += 256) {
    int j = idx & 7, lane = (idx >> 3) & 63, ks = (idx >> 9) & 3, nt = idx >> 11;
    int n = nt * 16 + (lane & 15);
    int k = ks * 32 + (lane >> 4) * 8 + j;
    float x = src[(size_t)n * HID + k];
    unsigned short h = f2bf(x);
    hi[idx] = h;
    lo[idx] = f2bf(x - bf2f(h));
  }
}

// ================= k_pre: bucket-scatter (4 edges/thr, r4-proven) + layer-0 mproj + qv0 =======
// r5 lesson: 1 edge/thread scatter = 104us (no per-thread atomic ILP); 4/thread = 72-97us.
// Fused so scatter's atomic latency hides under the MFMA blocks' compute (r4: 97us combined).
struct PreArgs {
  const int *src0, *dst0, *src1, *dst1;
  int *cnt0, *cnt1, *colB0, *colB1;
  const float* x_op; const unsigned short* FW; const float *bq, *CB;
  float* Pq; unsigned int *Pkv0, *Pkv1;
  const float *x_v, *Wq1, *bq1; float* qv;
};

__launch_bounds__(256)
__global__ void k_pre(PreArgs a) {
  __shared__ SMu sm;
  int bx = blockIdx.x, t = threadIdx.x;
  if (bx < E0E / 1024) {                     // edge0 bucket scatter: pos = atomic count
    int base = bx * 1024 + t;
    #pragma unroll
    for (int i = 0; i < 4; ++i) {
      int e = base + i * 256;
      int d = a.dst0[e];
      int pos = atomicAdd(&a.cnt0[d], 1);
      if (pos < CAP0) a.colB0[((size_t)d << 6) + pos] = a.src0[e];
    }
    return;
  }
  bx -= E0E / 1024;
  if (bx < NN / 1024) {                      // edge1 bucket scatter
    int base = bx * 1024 + t;
    #pragma unroll
    for (int i = 0; i < 4; ++i) {
      int e = base + i * 256;
      int d = a.dst1[e];
      int pos = atomicAdd(&a.cnt1[d], 1);
      if (pos < CAP1) a.colB1[((size_t)d << 10) + pos] = a.src1[e];
    }
    return;
  }
  bx -= NN / 1024;
  if (bx < NN / 64) {                        // layer-0 projection: q + kv0 + kv1, A staged once
    int m0 = bx * 64;
    stage_A(sm.a.Ah, sm.a.Al, t, a.x_op, m0, 0);
    __syncthreads();
    mproj3(sm.a.Ah, sm.a.Al, t, m0, a.FW + (size_t)16 * 32768, a.FW, a.bq, a.CB,
           a.Pq, a.Pkv0, a.Pkv1);
    return;
  }
  bx -= NN / 64;                             // qv0 for vnode bx
  if (t < HID) sm.v.xr[t] = a.x_v[bx * HID + t];
  __syncthreads();
  if (t < HID) {
    float s = a.bq1[t];
    const float4* wr = (const float4*)(a.Wq1 + (size_t)t * HID);
    const float4* xx = (const float4*)sm.v.xr;
    #pragma unroll 8
    for (int c = 0; c < HID / 4; ++c) {
      float4 w4 = wr[c], x4 = xx[c];
      s += x4.x * w4.x + x4.y * w4.y + x4.z * w4.z + x4.w * w4.w;
    }
    a.qv[bx * HID + t] = s;
  }
}

// ================= k_edges: edge0 (blocks < NN/4) + edge1 (NN/4 .. +512), bucket CSR ==========
__launch_bounds__(256)
__global__ void k_edges(const float* __restrict__ Pq, const unsigned int* __restrict__ Pkv0,
                        const unsigned int* __restrict__ Pkv1,
                        const int* __restrict__ cnt0, const int* __restrict__ colB0,
                        float* __restrict__ agg, const float* __restrict__ qv,
                        const int* __restrict__ cnt1, const int* __restrict__ colB1,
                        float* __restrict__ part) {
  int lane = threadIdx.x & 63;
  if (blockIdx.x < NN / 4) {
    int n = blockIdx.x * 4 + (threadIdx.x >> 6);
    float2 q = *(const float2*)(Pq + (size_t)n * HID + 2 * lane);
    int cnt = cnt0[n]; if (cnt > CAP0) cnt = CAP0;
    int e = n << 6, e1 = (n << 6) + cnt;
    float acc0 = 0.f, acc1 = 0.f, wsum = 0.f;
    for (; e + 8 <= e1; e += 8) {
      const uint2* r[8];
      #pragma unroll
      for (int u = 0; u < 8; ++u)
        r[u] = (const uint2*)(Pkv0 + ((size_t)colB0[e + u] << 7) + 2 * lane);
      uint2 kv[8];
      #pragma unroll
      for (int u = 0; u < 8; ++u) kv[u] = *r[u];
      float p[8];
      #pragma unroll
      for (int u = 0; u < 8; ++u)
        p[u] = q.x * f16lo(kv[u].x) + q.y * f16lo(kv[u].y);
      #pragma unroll
      for (int u = 0; u < 8; ++u) {
        p[u] += __shfl_xor(p[u], 1); p[u] += __shfl_xor(p[u], 2); p[u] += __shfl_xor(p[u], 4);
      }
      #pragma unroll
      for (int u = 0; u < 8; ++u) {
        float wg = __expf(p[u]);
        wsum += wg; acc0 += wg * f16hi(kv[u].x); acc1 += wg * f16hi(kv[u].y);
      }
    }
    for (; e < e1; ++e) {
      uint2 kv = *(const uint2*)(Pkv0 + ((size_t)colB0[e] << 7) + 2 * lane);
      float p = q.x * f16lo(kv.x) + q.y * f16lo(kv.y);
      p += __shfl_xor(p, 1); p += __shfl_xor(p, 2); p += __shfl_xor(p, 4);
      float wg = __expf(p);
      wsum += wg; acc0 += wg * f16hi(kv.x); acc1 += wg * f16hi(kv.y);
    }
    float inv = 1.0f / (wsum + 1e-16f);
    *(float2*)(agg + (size_t)n * HID + 2 * lane) = make_float2(acc0 * inv, acc1 * inv);
  } else {
    int b2 = blockIdx.x - NN / 4;
    int g = b2 >> 3, ch = b2 & 7;
    int w = threadIdx.x >> 6;
    int slot = ch * 4 + w;
    float2 q = *(const float2*)(qv + g * HID + 2 * lane);
    int tot = cnt1[g]; if (tot > CAP1) tot = CAP1;
    int base = g << 10;
    int len = (tot + 31) >> 5;
    int s0 = base + slot * len;
    int s1 = s0 + len; int lim = base + tot; if (s1 > lim) s1 = lim;
    float acc0 = 0.f, acc1 = 0.f, wsum = 0.f;
    int e = s0;
    for (; e + 4 <= s1; e += 4) {
      uint2 ka = *(const uint2*)(Pkv1 + ((size_t)colB1[e]     << 7) + 2 * lane);
      uint2 kb = *(const uint2*)(Pkv1 + ((size_t)colB1[e + 1] << 7) + 2 * lane);
      uint2 kc = *(const uint2*)(Pkv1 + ((size_t)colB1[e + 2] << 7) + 2 * lane);
      uint2 kd = *(const uint2*)(Pkv1 + ((size_t)colB1[e + 3] << 7) + 2 * lane);
      float pa = q.x * f16lo(ka.x) + q.y * f16lo(ka.y);
      float pb = q.x * f16lo(kb.x) + q.y * f16lo(kb.y);
      float pc = q.x * f16lo(kc.x) + q.y * f16lo(kc.y);
      float pd = q.x * f16lo(kd.x) + q.y * f16lo(kd.y);
      pa += __shfl_xor(pa, 1); pb += __shfl_xor(pb, 1); pc += __shfl_xor(pc, 1); pd += __shfl_xor(pd, 1);
      pa += __shfl_xor(pa, 2); pb += __shfl_xor(pb, 2); pc += __shfl_xor(pc, 2); pd += __shfl_xor(pd, 2);
      pa += __shfl_xor(pa, 4); pb += __shfl_xor(pb, 4); pc += __shfl_xor(pc, 4); pd += __shfl_xor(pd, 4);
      float wa = __expf(pa), wb = __expf(pb), wc = __expf(pc), wd = __expf(pd);
      wsum += (wa + wb) + (wc + wd);
      acc0 += wa * f16hi(ka.x) + wb * f16hi(kb.x) + wc * f16hi(kc.x) + wd * f16hi(kd.x);
      acc1 += wa * f16hi(ka.y) + wb * f16hi(kb.y) + wc * f16hi(kc.y) + wd * f16hi(kd.y);
    }
    for (; e < s1; ++e) {
      uint2 kv = *(const uint2*)(Pkv1 + ((size_t)colB1[e] << 7) + 2 * lane);
      float p = q.x * f16lo(kv.x) + q.y * f16lo(kv.y);
      p += __shfl_xor(p, 1); p += __shfl_xor(p, 2); p += __shfl_xor(p, 4);
      float ww = __expf(p);
      wsum += ww; acc0 += ww * f16hi(kv.x); acc1 += ww * f16hi(kv.y);
    }
    float* pp = part + (size_t)(g * 32 + slot) * 192;
    pp[lane] = acc0; pp[64 + lane] = acc1; pp[128 + lane] = wsum;
  }
}

// ================= k_post: out-GEMM + skip, then next-layer projection from the live tile =====
struct PArgs {
  const float *agg; const unsigned short *WaF_l; const float *ba_l0, *skip_l0, *xold;
  float *xop;
  const float *part, *Wa_l1, *ba_l1, *skip_l1, *xvold;
  float *xv, *outsv_l, *qv;
  const float *Wq_n1, *bq_n1;
  int do_qv;
  const unsigned short *WqF_n, *CWF_n;   // next-layer frag weights
  const float *bq_n0, *CB_n;
  float *Pq; unsigned int *Pkv0, *Pkv1;
  int do_proj;
};

__launch_bounds__(256)
__global__ void k_post(PArgs f) {
  __shared__ SMu sm;
  const int t = threadIdx.x;
  if (blockIdx.x >= NN / 64) {
    // ---- vnode tail: edge1red + gelu + Wa[l,1] + skip -> xv, outsv; then qv(l+1) ----
    int v = blockIdx.x - NN / 64;
    if (t < 64) {
      float a0 = 0.f, a1 = 0.f, ws2 = 0.f;
      for (int s = 0; s < 32; ++s) {
        const float* p = f.part + (size_t)(v * 32 + s) * 192;
        a0 += p[t]; a1 += p[64 + t]; ws2 += p[128 + t];
      }
      float inv = 1.0f / (ws2 + 1e-16f);
      sm.v.xr[2 * t]     = gelu_f(a0 * inv);
      sm.v.xr[2 * t + 1] = gelu_f(a1 * inv);
    }
    __syncthreads();
    if (t < HID) {
      float s = f.ba_l1[t];
      const float4* wr = (const float4*)(f.Wa_l1 + (size_t)t * HID);
      const float4* xx = (const float4*)sm.v.xr;
      #pragma unroll 8
      for (int c = 0; c < HID / 4; ++c) {
        float4 w4 = wr[c], x4 = xx[c];
        s += x4.x * w4.x + x4.y * w4.y + x4.z * w4.z + x4.w * w4.w;
      }
      float gg = sigmoid_f(*f.skip_l1);
      float nv2 = gg * s + (1.f - gg) * f.xvold[v * HID + t];
      f.xv[v * HID + t] = nv2;
      f.outsv_l[v * HID + t] = nv2;
      sm.v.xn[t] = nv2;
    }
    __syncthreads();
    if (f.do_qv && t < HID) {
      float s = f.bq_n1[t];
      const float4* wr = (const float4*)(f.Wq_n1 + (size_t)t * HID);
      const float4* xx = (const float4*)sm.v.xn;
      #pragma unroll 8
      for (int c = 0; c < HID / 4; ++c) {
        float4 w4 = wr[c], x4 = xx[c];
        s += x4.x * w4.x + x4.y * w4.y + x4.z * w4.z + x4.w * w4.w;
      }
      f.qv[v * HID + t] = s;
    }
    return;
  }
  const int m0 = blockIdx.x * 64;
  // post(l): xop = g*(gelu(agg)@Wa^T + ba) + (1-g)*xold
  stage_A(sm.a.Ah, sm.a.Al, t, f.agg, m0, 1);
  __syncthreads();
  f32x4 acc[2][4] = {};
  mfma_pass(sm.a.Ah, sm.a.Al, t, f.WaF_l, acc);
  const int w = t >> 6, c16 = t & 15, quad = (t & 63) >> 4;
  float g = sigmoid_f(*f.skip_l0), gm1 = 1.0f - g;
  #pragma unroll
  for (int j = 0; j < 2; ++j) {
    const int col = (2 * w + j) * 16 + c16;
    const float bb = f.ba_l0[col];
    #pragma unroll
    for (int s = 0; s < 4; ++s)
      #pragma unroll
      for (int r = 0; r < 4; ++r) {
        int lm = 16 * s + quad * 4 + r;
        float v = acc[j][s][r] + bb;
        v = g * v + gm1 * f.xold[(size_t)(m0 + lm) * HID + col];
        acc[j][s][r] = v;                         // keep for re-stage
        f.xop[(size_t)(m0 + lm) * HID + col] = v;
      }
  }
  if (!f.do_proj) return;                         // uniform across grid: all op-blocks agree
  __syncthreads();                                // all waves done reading old A tile
  #pragma unroll
  for (int j = 0; j < 2; ++j) {
    const int col = (2 * w + j) * 16 + c16;
    #pragma unroll
    for (int s = 0; s < 4; ++s)
      #pragma unroll
      for (int r = 0; r < 4; ++r) {
        int lm = 16 * s + quad * 4 + r;
        float v = acc[j][s][r];
        unsigned short h = f2bf(v);
        sm.a.Ah[lm][col] = h;
        sm.a.Al[lm][col] = f2bf(v - bf2f(h));
      }
  }
  __syncthreads();
  mproj3(sm.a.Ah, sm.a.Al, t, m0, f.WqF_n, f.CWF_n, f.bq_n0, f.CB_n, f.Pq, f.Pkv0, f.Pkv1);
}

// ================= JK attention + node/graph MLPs =============================================
struct TailW {
  const float *win, *bin, *wout, *bout;
  const float *nw0, *nb0, *nw1, *nb1, *nw2, *nb2, *nw3, *nb3, *nw4, *nb4, *nw5, *nb5, *nw6, *nb6;
  const float *gw0, *gb0, *gw1, *gb1;
};

__launch_bounds__(128)
__global__ void k_final(const float* __restrict__ outsv, TailW tw, float* __restrict__ outp) {
  __shared__ float xs[4][HID], qq[4][HID], kk[4][HID], vv[4][HID], oo[4][HID];
  __shared__ float att[NH][4][4];
  __shared__ float hb[HID], tb[64];
  int b = blockIdx.x, t = threadIdx.x;
  for (int l = 0; l < 4; ++l) xs[l][t] = outsv[(size_t)(l * NV + b) * HID + t];
  __syncthreads();
  for (int l = 0; l < 4; ++l) {
    float sq = tw.bin[t], sk = tw.bin[t + 128], sv = tw.bin[t + 256];
    const float* wq = tw.win + (size_t)t * HID;
    const float* wk = tw.win + (size_t)(t + 128) * HID;
    const float* wv = tw.win + (size_t)(t + 256) * HID;
    for (int c = 0; c < HID; ++c) {
      float x = xs[l][c];
      sq += x * wq[c]; sk += x * wk[c]; sv += x * wv[c];
    }
    qq[l][t] = sq; kk[l][t] = sk; vv[l][t] = sv;
  }
  __syncthreads();
  {
    int h = t >> 4, ql = (t >> 2) & 3, kl = t & 3;
    float s = 0.f;
    #pragma unroll
    for (int d = 0; d < DH; ++d) s += qq[ql][h * DH + d] * kk[kl][h * DH + d];
    att[h][ql][kl] = s * SCALE;
  }
  __syncthreads();
  if (t < 32) {
    int h = t >> 2, ql = t & 3;
    float m = att[h][ql][0];
    for (int k2 = 1; k2 < 4; ++k2) m = fmaxf(m, att[h][ql][k2]);
    float e[4], s = 0.f;
    for (int k2 = 0; k2 < 4; ++k2) { e[k2] = __expf(att[h][ql][k2] - m); s += e[k2]; }
    for (int k2 = 0; k2 < 4; ++k2) att[h][ql][k2] = e[k2] / s;
  }
  __syncthreads();
  {
    int h = t >> 4;
    #pragma unroll
    for (int ql = 0; ql < 4; ++ql) {
      float s = 0.f;
      #pragma unroll
      for (int kl = 0; kl < 4; ++kl) s += att[h][ql][kl] * vv[kl][t];
      oo[ql][t] = s;
    }
  }
  __syncthreads();
  {
    float s = 0.f;
    const float* wr = tw.wout + (size_t)t * HID;
    for (int l = 0; l < 4; ++l) {
      float ss = tw.bout[t];
      for (int c = 0; c < HID; ++c) ss += oo[l][c] * wr[c];
      s += ss;
    }
    hb[t] = s;
  }
  __syncthreads();
  if (t < 64) { float s = tw.nb0[t]; const float* wr = tw.nw0 + t * 128; for (int c = 0; c < 128; ++c) s += hb[c] * wr[c]; tb[t] = gelu_f(s); }
  __syncthreads();
  if (t < 32) { float s = tw.nb1[t]; const float* wr = tw.nw1 + t * 64;  for (int c = 0; c < 64;  ++c) s += tb[c] * wr[c]; hb[t] = gelu_f(s); }
  __syncthreads();
  if (t < 16) { float s = tw.nb2[t]; const float* wr = tw.nw2 + t * 32;  for (int c = 0; c < 32;  ++c) s += hb[c] * wr[c]; tb[t] = gelu_f(s); }
  __syncthreads();
  if (t < 8)  { float s = tw.nb3[t]; const float* wr = tw.nw3 + t * 16;  for (int c = 0; c < 16;  ++c) s += tb[c] * wr[c]; hb[t] = gelu_f(s); }
  __syncthreads();
  if (t < 4)  { float s = tw.nb4[t]; const float* wr = tw.nw4 + t * 8;   for (int c = 0; c < 8;   ++c) s += hb[c] * wr[c]; tb[t] = gelu_f(s); }
  __syncthreads();
  if (t < 2)  { float s = tw.nb5[t]; const float* wr = tw.nw5 + t * 4;   for (int c = 0; c < 4;   ++c) s += tb[c] * wr[c]; hb[t] = gelu_f(s); }
  __syncthreads();
  if (t == 0) {
    float s = hb[0] * tw.nw6[0] + hb[1] * tw.nw6[1] + tw.nb6[0];
    float g0 = gelu_f(s * tw.gw0[0] + tw.gb0[0]);
    float g1 = gelu_f(s * tw.gw0[1] + tw.gb0[1]);
    outp[b] = g0 * tw.gw1[0] + g1 * tw.gw1[1] + tw.gb1[0];
  }
}

// ================= host =======================================================================
extern "C" void kernel_launch(void* const* d_in, const int* in_sizes, int n_in,
                              void* d_out, int out_size, void* d_ws, size_t ws_size,
                              hipStream_t stream) {
  const float* x_op = (const float*)d_in[0];
  const float* x_v  = (const float*)d_in[1];
  const int*   ei0  = (const int*)d_in[2];
  const int*   ei1  = (const int*)d_in[3];
  const float* Wk   = (const float*)d_in[4];
  const float* Wq   = (const float*)d_in[5];
  const float* Wv   = (const float*)d_in[6];
  const float* Wa   = (const float*)d_in[7];
  const float* bk   = (const float*)d_in[8];
  const float* bq   = (const float*)d_in[9];
  const float* bv   = (const float*)d_in[10];
  const float* ba   = (const float*)d_in[11];
  const float* skip = (const float*)d_in[12];
  const float* a_rel = (const float*)d_in[13];
  const float* m_rel = (const float*)d_in[14];
  const float* p_rel = (const float*)d_in[15];
  (void)in_sizes; (void)n_in; (void)out_size; (void)ws_size;

  char* wsp = (char*)d_ws;
  size_t off = 0;
  auto alloc = [&](size_t bytes) -> void* {
    void* p = wsp + off;
    off += (bytes + 255) & ~(size_t)255;
    return p;
  };
  float* Pq    = (float*)alloc((size_t)NN * HID * 4);
  unsigned int* Pkv0 = (unsigned int*)alloc((size_t)NN * HID * 4);  // fp16 k|v packed per dword
  unsigned int* Pkv1 = (unsigned int*)alloc((size_t)NN * HID * 4);
  float* xop   = (float*)alloc((size_t)NN * HID * 4);
  float* agg   = (float*)alloc((size_t)NN * HID * 4);
  float* CW    = (float*)alloc((size_t)16 * HID * HID * 4);
  float* CB    = (float*)alloc((size_t)16 * HID * 4);
  unsigned short* FW = (unsigned short*)alloc((size_t)24 * 32768 * 2);  // 1.57 MB frag weights
  float* xv    = (float*)alloc((size_t)NV * HID * 4);
  float* qv    = (float*)alloc((size_t)NV * HID * 4);
  float* outsv = (float*)alloc((size_t)NL * NV * HID * 4);
  float* part  = (float*)alloc((size_t)NV * 32 * 192 * 4);
  int* cnt0    = (int*)alloc((size_t)NN * 4);
  int* colB0   = (int*)alloc((size_t)NN * CAP0 * 4);   // 8 MB fixed-cap buckets
  int* cnt1    = (int*)alloc((size_t)NV * 4);
  int* colB1   = (int*)alloc((size_t)NV * CAP1 * 4);

  hipMemsetAsync(cnt0, 0, (size_t)NN * 4, stream);
  hipMemsetAsync(cnt1, 0, (size_t)NV * 4, stream);

  k_setup<<<16, 256, 0, stream>>>(Wk, Wv, bk, bv, a_rel, m_rel, p_rel, CW, CB);
  k_frag<<<24, 256, 0, stream>>>(CW, Wq, Wa, FW);

  PreArgs pa;
  pa.src0 = ei0; pa.dst0 = ei0 + E0E;
  pa.src1 = ei1; pa.dst1 = ei1 + NN;
  pa.cnt0 = cnt0; pa.cnt1 = cnt1; pa.colB0 = colB0; pa.colB1 = colB1;
  pa.x_op = x_op; pa.FW = FW; pa.bq = bq; pa.CB = CB;
  pa.Pq = Pq; pa.Pkv0 = Pkv0; pa.Pkv1 = Pkv1;
  pa.x_v = x_v; pa.Wq1 = Wq + (size_t)1 * HID * HID; pa.bq1 = bq + HID; pa.qv = qv;
  k_pre<<<E0E / 1024 + NN / 1024 + NN / 64 + NV, 256, 0, stream>>>(pa);

  for (int l = 0; l < NL; ++l) {
    k_edges<<<NN / 4 + NV * 8, 256, 0, stream>>>(Pq, Pkv0, Pkv1, cnt0, colB0, agg,
                                                 qv, cnt1, colB1, part);
    PArgs f;
    f.agg = agg;
    f.WaF_l = FW + (size_t)(20 + l) * 32768;
    f.ba_l0 = ba + (l * 2 + 0) * HID;
    f.skip_l0 = skip + l * 2 + 0;
    f.xold = (l == 0) ? x_op : xop;
    f.xop = xop;
    f.part = part;
    f.Wa_l1 = Wa + (size_t)(l * 2 + 1) * HID * HID;
    f.ba_l1 = ba + (l * 2 + 1) * HID;
    f.skip_l1 = skip + l * 2 + 1;
    f.xvold = (l == 0) ? x_v : xv;
    f.xv = xv;
    f.outsv_l = outsv + (size_t)l * NV * HID;
    f.qv = qv;
    int ln = (l + 1) & 3;
    f.Wq_n1 = Wq + (size_t)(ln * 2 + 1) * HID * HID;
    f.bq_n1 = bq + (ln * 2 + 1) * HID;
    f.do_qv = (l < NL - 1) ? 1 : 0;
    f.WqF_n = FW + (size_t)(16 + ln) * 32768;
    f.CWF_n = FW + (size_t)(ln * 4) * 32768;
    f.bq_n0 = bq + (ln * 2 + 0) * HID;
    f.CB_n  = CB + ln * 4 * HID;
    f.Pq = Pq; f.Pkv0 = Pkv0; f.Pkv1 = Pkv1;
    f.do_proj = (l < NL - 1) ? 1 : 0;
    k_post<<<NN / 64 + NV, 256, 0, stream>>>(f);
  }

  TailW tw;
  tw.win  = (const float*)d_in[16]; tw.bin  = (const float*)d_in[17];
  tw.wout = (const float*)d_in[18]; tw.bout = (const float*)d_in[19];
  tw.nw0 = (const float*)d_in[20]; tw.nb0 = (const float*)d_in[21];
  tw.nw1 = (const float*)d_in[22]; tw.nb1 = (const float*)d_in[23];
  tw.nw2 = (const float*)d_in[24]; tw.nb2 = (const float*)d_in[25];
  tw.nw3 = (const float*)d_in[26]; tw.nb3 = (const float*)d_in[27];
  tw.nw4 = (const float*)d_in[28]; tw.nb4 = (const float*)d_in[29];
  tw.nw5 = (const float*)d_in[30]; tw.nb5 = (const float*)d_in[31];
  tw.nw6 = (const float*)d_in[32]; tw.nb6 = (const float*)d_in[33];
  tw.gw0 = (const float*)d_in[34]; tw.gb0 = (const float*)d_in[35];
  tw.gw1 = (const float*)d_in[36]; tw.gb1 = (const float*)d_in[37];
  k_final<<<NV, 128, 0, stream>>>(outsv, tw, (float*)d_out);
}

// Round 7
// 698.097 us; speedup vs baseline: 1.0579x; 1.0209x over previous
//
#include <hip/hip_runtime.h>

#define NN   32768
#define NV   64
#define E0E  524288
#define HID  128
#define NL   4
#define NH   8
#define DH   16
#define SCALE 0.25f
#define LDA  136   // bf16 row stride for staged A (16B-aligned frag reads, 2-way bank alias)
#define CAP0 64    // edge0 bucket capacity (multinomial ~Poisson(16), 12-sigma safe)
#define CAP1 1024  // edge1 bucket capacity (~Poisson(512), 22-sigma safe)

typedef __attribute__((ext_vector_type(8))) short short8;   // 8 bf16 = 4 VGPRs
typedef __attribute__((ext_vector_type(4))) float f32x4;

__device__ __forceinline__ float gelu_f(float x) {
  return 0.5f * x * (1.0f + erff(x * 0.7071067811865475f));
}
__device__ __forceinline__ float sigmoid_f(float x) {
  return 1.0f / (1.0f + __expf(-x));
}
__device__ __forceinline__ unsigned short f2bf(float x) {   // RN-even f32->bf16
  unsigned u = __float_as_uint(x);
  return (unsigned short)((u + 0x7FFFu + ((u >> 16) & 1u)) >> 16);
}
__device__ __forceinline__ float bf2f(unsigned short h) {
  return __uint_as_float(((unsigned)h) << 16);
}
// fp16 conversions via native _Float16 (no hip_fp16.h dependency)
__device__ __forceinline__ unsigned short f2h(float x) {
  union { _Float16 h; unsigned short u; } cv;
  cv.h = (_Float16)x;
  return cv.u;
}
__device__ __forceinline__ float h2f(unsigned short u) {
  union { _Float16 h; unsigned short u; } cv;
  cv.u = u;
  return (float)cv.h;
}
__device__ __forceinline__ float f16lo(unsigned u) { return h2f((unsigned short)(u & 0xffffu)); }
__device__ __forceinline__ float f16hi(unsigned u) { return h2f((unsigned short)(u >> 16)); }

union SMu {
  struct { unsigned short Ah[64][LDA]; unsigned short Al[64][LDA]; } a;  // 34816 B
  struct { float xr[HID]; float xn[HID]; } v;
};

// ---- stage 64xK=128 fp32 tile into split hi/lo bf16 LDS (coalesced float4 reads) ----
__device__ __forceinline__ void stage_A(unsigned short Ah[][LDA], unsigned short Al[][LDA],
                                        int t, const float* __restrict__ A, int m0, int gelu) {
  #pragma unroll
  for (int i = 0; i < 8; ++i) {
    int idx = t + 256 * i;            // float4 index over 64x32
    int m = idx >> 5, c4 = (idx & 31) * 4;
    float4 v = *(const float4*)(A + (size_t)(m0 + m) * HID + c4);
    if (gelu) { v.x = gelu_f(v.x); v.y = gelu_f(v.y); v.z = gelu_f(v.z); v.w = gelu_f(v.w); }
    unsigned short h0 = f2bf(v.x), h1 = f2bf(v.y), h2 = f2bf(v.z), h3 = f2bf(v.w);
    *(ushort4*)&Ah[m][c4] = make_ushort4(h0, h1, h2, h3);
    *(ushort4*)&Al[m][c4] = make_ushort4(f2bf(v.x - bf2f(h0)), f2bf(v.y - bf2f(h1)),
                                         f2bf(v.z - bf2f(h2)), f2bf(v.w - bf2f(h3)));
  }
}

// ---- MFMA split-bf16 single pass: 64x128 tile, K=128, B-reuse form (96 MFMAs/wave) ----
__device__ __forceinline__ void mfma_pass(const unsigned short Ah[][LDA],
    const unsigned short Al[][LDA], int t, const unsigned short* __restrict__ Wf,
    f32x4 acc[2][4]) {
  const int w = t >> 6, lane = t & 63, c16 = lane & 15, quad = lane >> 4;
  #pragma unroll
  for (int ks = 0; ks < 4; ++ks) {
    short8 ah[4], al[4];
    #pragma unroll
    for (int s = 0; s < 4; ++s) {
      ah[s] = *(const short8*)&Ah[16 * s + c16][ks * 32 + quad * 8];
      al[s] = *(const short8*)&Al[16 * s + c16][ks * 32 + quad * 8];
    }
    #pragma unroll
    for (int j = 0; j < 2; ++j) {
      const unsigned short* bp = Wf + (size_t)(((2 * w + j) * 4 + ks) * 64 + lane) * 8;
      short8 bh = *(const short8*)bp;
      short8 bl = *(const short8*)(bp + 16384);
      #pragma unroll
      for (int s = 0; s < 4; ++s) {
        acc[j][s] = __builtin_amdgcn_mfma_f32_16x16x32_bf16(ah[s], bh, acc[j][s], 0, 0, 0);
        acc[j][s] = __builtin_amdgcn_mfma_f32_16x16x32_bf16(ah[s], bl, acc[j][s], 0, 0, 0);
        acc[j][s] = __builtin_amdgcn_mfma_f32_16x16x32_bf16(al[s], bh, acc[j][s], 0, 0, 0);
      }
    }
  }
}

// ---- q slice: 1 pass + fp32 write ----
__device__ __forceinline__ void proj_q(const unsigned short Ah[][LDA],
    const unsigned short Al[][LDA], int t, int m0,
    const unsigned short* __restrict__ WqF, const float* __restrict__ bq0,
    float* __restrict__ Pq) {
  const int w = t >> 6, c16 = t & 15, quad = (t & 63) >> 4;
  f32x4 acc[2][4] = {};
  mfma_pass(Ah, Al, t, WqF, acc);
  #pragma unroll
  for (int j = 0; j < 2; ++j) {
    const int col = (2 * w + j) * 16 + c16;
    const float bb = bq0[col];
    #pragma unroll
    for (int s = 0; s < 4; ++s)
      #pragma unroll
      for (int r = 0; r < 4; ++r) {
        int m = m0 + 16 * s + quad * 4 + r;
        Pq[(size_t)m * HID + col] = acc[j][s][r] + bb;
      }
  }
}

// ---- k|v slice: K pass (packed to 16 u32) then V pass, fp16 pair write ----
__device__ __forceinline__ void proj_kv(const unsigned short Ah[][LDA],
    const unsigned short Al[][LDA], int t, int m0,
    const unsigned short* __restrict__ WfK, const float* __restrict__ bK,
    const float* __restrict__ bV, unsigned int* __restrict__ dst) {
  const int w = t >> 6, c16 = t & 15, quad = (t & 63) >> 4;
  unsigned kp[2][4][2];
  {
    f32x4 accK[2][4] = {};
    mfma_pass(Ah, Al, t, WfK, accK);
    #pragma unroll
    for (int j = 0; j < 2; ++j) {
      const float bbk = bK[(2 * w + j) * 16 + c16];
      #pragma unroll
      for (int s = 0; s < 4; ++s)
        #pragma unroll
        for (int rr = 0; rr < 2; ++rr)
          kp[j][s][rr] = (unsigned)f2h(accK[j][s][2 * rr] + bbk)
                       | ((unsigned)f2h(accK[j][s][2 * rr + 1] + bbk) << 16);
    }
  }
  f32x4 accV[2][4] = {};
  mfma_pass(Ah, Al, t, WfK + 32768, accV);
  #pragma unroll
  for (int j = 0; j < 2; ++j) {
    const int col = (2 * w + j) * 16 + c16;
    const float bbv = bV[col];
    #pragma unroll
    for (int s = 0; s < 4; ++s)
      #pragma unroll
      for (int r = 0; r < 4; ++r) {
        int m = m0 + 16 * s + quad * 4 + r;
        unsigned pk = (kp[j][s][r >> 1] >> ((r & 1) * 16)) & 0xffffu;
        unsigned pv = (unsigned)f2h(accV[j][s][r] + bbv);
        dst[(size_t)m * HID + col] = pk | (pv << 16);
      }
  }
}

// ================= k_setup: weight-combine only (16 blocks; cnt zeroing via memset) ===========
__global__ __launch_bounds__(256) void k_setup(
    const float* __restrict__ Wk, const float* __restrict__ Wv,
    const float* __restrict__ bk, const float* __restrict__ bv,
    const float* __restrict__ a_rel, const float* __restrict__ m_rel,
    const float* __restrict__ p_rel,
    float* __restrict__ CW, float* __restrict__ CB) {
  int blk = blockIdx.x, t = threadIdx.x;   // 0..15: l*4 + {K0,V0,K1,V1}
  int l = blk >> 2, mat = blk & 3;
  int rel = mat >> 1;
  int isK = ((mat & 1) == 0);
  const float* W  = (isK ? Wk : Wv) + (size_t)(l * 2) * HID * HID;
  const float* bb = (isK ? bk : bv) + (l * 2) * HID;
  const float* R  = (isK ? a_rel : m_rel) + (size_t)((l * 2 + rel) * NH) * DH * DH;
  float* cw = CW + (size_t)blk * HID * HID;
  float* cb = CB + blk * HID;
  for (int o = t; o < HID * HID; o += 256) {
    int j = o >> 7, c = o & 127;
    int h = j >> 4, e = j & 15;
    float sc = isK ? (p_rel[(l * 2 + rel) * NH + h] * SCALE) : 1.0f;
    float s = 0.f;
    #pragma unroll
    for (int d = 0; d < DH; ++d)
      s += W[(size_t)(h * DH + d) * HID + c] * R[h * 256 + d * 16 + e];
    cw[(size_t)j * HID + c] = s * sc;   // [n][k]
  }
  if (t < HID) {
    int j = t, h = j >> 4, e = j & 15;
    float sc = isK ? (p_rel[(l * 2 + rel) * NH + h] * SCALE) : 1.0f;
    float s = 0.f;
    #pragma unroll
    for (int d = 0; d < DH; ++d) s += bb[h * DH + d] * R[h * 256 + d * 16 + e];
    cb[j] = s * sc;
  }
}

// ================= frag-order + split all 24 weight mats (CW 0-15, Wq0 16-19, Wa0 20-23) ======
__global__ __launch_bounds__(256) void k_frag(const float* __restrict__ CW,
                                              const float* __restrict__ Wq,
                                              const float* __restrict__ Wa,
                                              unsigned short* __restrict__ FW) {
  int m = blockIdx.x, t = threadIdx.x;
  const float* src = (m < 16) ? (CW + (size_t)m * HID * HID)
                   : (m < 20) ? (Wq + (size_t)((m - 16) * 2) * HID * HID)
                              : (Wa + (size_t)((m - 20) * 2) * HID * HID);
  unsigned short* hi = FW + (size_t)m * 32768;
  unsigned short* lo = hi + 16384;
  for (int idx = t; idx < 16384; idx += 256) {
    int j = idx & 7, lane = (idx >> 3) & 63, ks = (idx >> 9) & 3, nt = idx >> 11;
    int n = nt * 16 + (lane & 15);
    int k = ks * 32 + (lane >> 4) * 8 + j;
    float x = src[(size_t)n * HID + k];
    unsigned short h = f2bf(x);
    hi[idx] = h;
    lo[idx] = f2bf(x - bf2f(h));
  }
}

// ================= k_pre: bucket-scatter (4/thr) + layer-0 proj (y-sliced, 3 blk/tile) + qv0 ==
// r6 lesson: one block per tile running 5 serial proj passes -> 2.25 blk/CU, everything idle.
// 3 slice-blocks per tile (q | kv0 | kv1) triple parallelism; x_op re-reads are L3 hits.
struct PreArgs {
  const int *src0, *dst0, *src1, *dst1;
  int *cnt0, *cnt1, *colB0, *colB1;
  const float* x_op; const unsigned short* FW; const float *bq, *CB;
  float* Pq; unsigned int *Pkv0, *Pkv1;
  const float *x_v, *Wq1, *bq1; float* qv;
};

__launch_bounds__(256)
__global__ void k_pre(PreArgs a) {
  __shared__ SMu sm;
  int bx = blockIdx.x, t = threadIdx.x;
  if (bx < E0E / 1024) {                     // edge0 bucket scatter: pos = atomic count
    int base = bx * 1024 + t;
    #pragma unroll
    for (int i = 0; i < 4; ++i) {
      int e = base + i * 256;
      int d = a.dst0[e];
      int pos = atomicAdd(&a.cnt0[d], 1);
      if (pos < CAP0) a.colB0[((size_t)d << 6) + pos] = a.src0[e];
    }
    return;
  }
  bx -= E0E / 1024;
  if (bx < NN / 1024) {                      // edge1 bucket scatter
    int base = bx * 1024 + t;
    #pragma unroll
    for (int i = 0; i < 4; ++i) {
      int e = base + i * 256;
      int d = a.dst1[e];
      int pos = atomicAdd(&a.cnt1[d], 1);
      if (pos < CAP1) a.colB1[((size_t)d << 10) + pos] = a.src1[e];
    }
    return;
  }
  bx -= NN / 1024;
  if (bx < 3 * (NN / 64)) {                  // layer-0 projection slice: tile | slice y
    int y = bx >> 9, tile = bx & 511;
    int m0 = tile * 64;
    stage_A(sm.a.Ah, sm.a.Al, t, a.x_op, m0, 0);
    __syncthreads();
    if (y == 0)      proj_q (sm.a.Ah, sm.a.Al, t, m0, a.FW + (size_t)16 * 32768, a.bq, a.Pq);
    else if (y == 1) proj_kv(sm.a.Ah, sm.a.Al, t, m0, a.FW, a.CB, a.CB + HID, a.Pkv0);
    else             proj_kv(sm.a.Ah, sm.a.Al, t, m0, a.FW + (size_t)2 * 32768,
                             a.CB + 2 * HID, a.CB + 3 * HID, a.Pkv1);
    return;
  }
  bx -= 3 * (NN / 64);                       // qv0 for vnode bx
  if (t < HID) sm.v.xr[t] = a.x_v[bx * HID + t];
  __syncthreads();
  if (t < HID) {
    float s = a.bq1[t];
    const float4* wr = (const float4*)(a.Wq1 + (size_t)t * HID);
    const float4* xx = (const float4*)sm.v.xr;
    #pragma unroll 8
    for (int c = 0; c < HID / 4; ++c) {
      float4 w4 = wr[c], x4 = xx[c];
      s += x4.x * w4.x + x4.y * w4.y + x4.z * w4.z + x4.w * w4.w;
    }
    a.qv[bx * HID + t] = s;
  }
}

// ================= k_edges: edge0 (blocks < e0blocks; DEAD at l=3) + edge1 =====================
__launch_bounds__(256)
__global__ void k_edges(const float* __restrict__ Pq, const unsigned int* __restrict__ Pkv0,
                        const unsigned int* __restrict__ Pkv1,
                        const int* __restrict__ cnt0, const int* __restrict__ colB0,
                        float* __restrict__ agg, const float* __restrict__ qv,
                        const int* __restrict__ cnt1, const int* __restrict__ colB1,
                        float* __restrict__ part, int e0blocks) {
  int lane = threadIdx.x & 63;
  if (blockIdx.x < e0blocks) {
    int n = blockIdx.x * 4 + (threadIdx.x >> 6);
    float2 q = *(const float2*)(Pq + (size_t)n * HID + 2 * lane);
    int cnt = cnt0[n]; if (cnt > CAP0) cnt = CAP0;
    int e = n << 6, e1 = (n << 6) + cnt;
    float acc0 = 0.f, acc1 = 0.f, wsum = 0.f;
    for (; e + 8 <= e1; e += 8) {
      const uint2* r[8];
      #pragma unroll
      for (int u = 0; u < 8; ++u)
        r[u] = (const uint2*)(Pkv0 + ((size_t)colB0[e + u] << 7) + 2 * lane);
      uint2 kv[8];
      #pragma unroll
      for (int u = 0; u < 8; ++u) kv[u] = *r[u];
      float p[8];
      #pragma unroll
      for (int u = 0; u < 8; ++u)
        p[u] = q.x * f16lo(kv[u].x) + q.y * f16lo(kv[u].y);
      #pragma unroll
      for (int u = 0; u < 8; ++u) {
        p[u] += __shfl_xor(p[u], 1); p[u] += __shfl_xor(p[u], 2); p[u] += __shfl_xor(p[u], 4);
      }
      #pragma unroll
      for (int u = 0; u < 8; ++u) {
        float wg = __expf(p[u]);
        wsum += wg; acc0 += wg * f16hi(kv[u].x); acc1 += wg * f16hi(kv[u].y);
      }
    }
    for (; e < e1; ++e) {
      uint2 kv = *(const uint2*)(Pkv0 + ((size_t)colB0[e] << 7) + 2 * lane);
      float p = q.x * f16lo(kv.x) + q.y * f16lo(kv.y);
      p += __shfl_xor(p, 1); p += __shfl_xor(p, 2); p += __shfl_xor(p, 4);
      float wg = __expf(p);
      wsum += wg; acc0 += wg * f16hi(kv.x); acc1 += wg * f16hi(kv.y);
    }
    float inv = 1.0f / (wsum + 1e-16f);
    *(float2*)(agg + (size_t)n * HID + 2 * lane) = make_float2(acc0 * inv, acc1 * inv);
  } else {
    int b2 = blockIdx.x - e0blocks;
    int g = b2 >> 3, ch = b2 & 7;
    int w = threadIdx.x >> 6;
    int slot = ch * 4 + w;
    float2 q = *(const float2*)(qv + g * HID + 2 * lane);
    int tot = cnt1[g]; if (tot > CAP1) tot = CAP1;
    int base = g << 10;
    int len = (tot + 31) >> 5;
    int s0 = base + slot * len;
    int s1 = s0 + len; int lim = base + tot; if (s1 > lim) s1 = lim;
    float acc0 = 0.f, acc1 = 0.f, wsum = 0.f;
    int e = s0;
    for (; e + 4 <= s1; e += 4) {
      uint2 ka = *(const uint2*)(Pkv1 + ((size_t)colB1[e]     << 7) + 2 * lane);
      uint2 kb = *(const uint2*)(Pkv1 + ((size_t)colB1[e + 1] << 7) + 2 * lane);
      uint2 kc = *(const uint2*)(Pkv1 + ((size_t)colB1[e + 2] << 7) + 2 * lane);
      uint2 kd = *(const uint2*)(Pkv1 + ((size_t)colB1[e + 3] << 7) + 2 * lane);
      float pa = q.x * f16lo(ka.x) + q.y * f16lo(ka.y);
      float pb = q.x * f16lo(kb.x) + q.y * f16lo(kb.y);
      float pc = q.x * f16lo(kc.x) + q.y * f16lo(kc.y);
      float pd = q.x * f16lo(kd.x) + q.y * f16lo(kd.y);
      pa += __shfl_xor(pa, 1); pb += __shfl_xor(pb, 1); pc += __shfl_xor(pc, 1); pd += __shfl_xor(pd, 1);
      pa += __shfl_xor(pa, 2); pb += __shfl_xor(pb, 2); pc += __shfl_xor(pc, 2); pd += __shfl_xor(pd, 2);
      pa += __shfl_xor(pa, 4); pb += __shfl_xor(pb, 4); pc += __shfl_xor(pc, 4); pd += __shfl_xor(pd, 4);
      float wa = __expf(pa), wb = __expf(pb), wc = __expf(pc), wd = __expf(pd);
      wsum += (wa + wb) + (wc + wd);
      acc0 += wa * f16hi(ka.x) + wb * f16hi(kb.x) + wc * f16hi(kc.x) + wd * f16hi(kd.x);
      acc1 += wa * f16hi(ka.y) + wb * f16hi(kb.y) + wc * f16hi(kc.y) + wd * f16hi(kd.y);
    }
    for (; e < s1; ++e) {
      uint2 kv = *(const uint2*)(Pkv1 + ((size_t)colB1[e] << 7) + 2 * lane);
      float p = q.x * f16lo(kv.x) + q.y * f16lo(kv.y);
      p += __shfl_xor(p, 1); p += __shfl_xor(p, 2); p += __shfl_xor(p, 4);
      float ww = __expf(p);
      wsum += ww; acc0 += ww * f16hi(kv.x); acc1 += ww * f16hi(kv.y);
    }
    float* pp = part + (size_t)(g * 32 + slot) * 192;
    pp[lane] = acc0; pp[64 + lane] = acc1; pp[128 + lane] = wsum;
  }
}

// ================= k_post: post-GEMM + y-sliced next-layer proj ================================
// mode 0 (l=0,1): grid (576,3) — each slice block redoes the cheap post pass, then 1-2 proj
//   passes; y0 also writes xop. mode 1 (l=2): grid 576 — post + rel1 kv only (Pq/Pkv0/xop are
//   dead: l=3 edge0 & op-post eliminated). mode 2 (l=3): grid 64 — vnode tail only.
struct PArgs {
  const float *agg; const unsigned short *WaF_l; const float *ba_l0, *skip_l0, *xold;
  float *xop;
  const float *part, *Wa_l1, *ba_l1, *skip_l1, *xvold;
  float *xv, *outsv_l, *qv;
  const float *Wq_n1, *bq_n1;
  int do_qv;
  const unsigned short *WqF_n, *CWF_n;   // next-layer frag weights
  const float *bq_n0, *CB_n;
  float *Pq; unsigned int *Pkv0, *Pkv1;
  int mode;
};

__device__ __forceinline__ void vtail(SMu& sm, int t, int v, const PArgs& f) {
  if (t < 64) {
    float a0 = 0.f, a1 = 0.f, ws2 = 0.f;
    for (int s = 0; s < 32; ++s) {
      const float* p = f.part + (size_t)(v * 32 + s) * 192;
      a0 += p[t]; a1 += p[64 + t]; ws2 += p[128 + t];
    }
    float inv = 1.0f / (ws2 + 1e-16f);
    sm.v.xr[2 * t]     = gelu_f(a0 * inv);
    sm.v.xr[2 * t + 1] = gelu_f(a1 * inv);
  }
  __syncthreads();
  if (t < HID) {
    float s = f.ba_l1[t];
    const float4* wr = (const float4*)(f.Wa_l1 + (size_t)t * HID);
    const float4* xx = (const float4*)sm.v.xr;
    #pragma unroll 8
    for (int c = 0; c < HID / 4; ++c) {
      float4 w4 = wr[c], x4 = xx[c];
      s += x4.x * w4.x + x4.y * w4.y + x4.z * w4.z + x4.w * w4.w;
    }
    float gg = sigmoid_f(*f.skip_l1);
    float nv2 = gg * s + (1.f - gg) * f.xvold[v * HID + t];
    f.xv[v * HID + t] = nv2;
    f.outsv_l[v * HID + t] = nv2;
    sm.v.xn[t] = nv2;
  }
  __syncthreads();
  if (f.do_qv && t < HID) {
    float s = f.bq_n1[t];
    const float4* wr = (const float4*)(f.Wq_n1 + (size_t)t * HID);
    const float4* xx = (const float4*)sm.v.xn;
    #pragma unroll 8
    for (int c = 0; c < HID / 4; ++c) {
      float4 w4 = wr[c], x4 = xx[c];
      s += x4.x * w4.x + x4.y * w4.y + x4.z * w4.z + x4.w * w4.w;
    }
    f.qv[v * HID + t] = s;
  }
}

__launch_bounds__(256)
__global__ void k_post(PArgs f) {
  __shared__ SMu sm;
  const int t = threadIdx.x;
  int bx = blockIdx.x;
  if (f.mode == 2) { vtail(sm, t, bx, f); return; }
  if (bx >= NN / 64) {
    if (blockIdx.y == 0) vtail(sm, t, bx - NN / 64, f);
    return;
  }
  const int m0 = bx * 64;
  const int y = blockIdx.y;
  // post(l): v = g*(gelu(agg)@Wa^T + ba) + (1-g)*xold  (recomputed per slice block; cheap)
  stage_A(sm.a.Ah, sm.a.Al, t, f.agg, m0, 1);
  __syncthreads();
  f32x4 acc[2][4] = {};
  mfma_pass(sm.a.Ah, sm.a.Al, t, f.WaF_l, acc);
  const int w = t >> 6, c16 = t & 15, quad = (t & 63) >> 4;
  float g = sigmoid_f(*f.skip_l0), gm1 = 1.0f - g;
  #pragma unroll
  for (int j = 0; j < 2; ++j) {
    const int col = (2 * w + j) * 16 + c16;
    const float bb = f.ba_l0[col];
    #pragma unroll
    for (int s = 0; s < 4; ++s)
      #pragma unroll
      for (int r = 0; r < 4; ++r) {
        int lm = 16 * s + quad * 4 + r;
        float v = acc[j][s][r] + bb;
        v = g * v + gm1 * f.xold[(size_t)(m0 + lm) * HID + col];
        acc[j][s][r] = v;                         // keep for re-stage
        if (f.mode == 0 && y == 0)
          f.xop[(size_t)(m0 + lm) * HID + col] = v;
      }
  }
  __syncthreads();                                // all waves done reading old A tile
  #pragma unroll
  for (int j = 0; j < 2; ++j) {
    const int col = (2 * w + j) * 16 + c16;
    #pragma unroll
    for (int s = 0; s < 4; ++s)
      #pragma unroll
      for (int r = 0; r < 4; ++r) {
        int lm = 16 * s + quad * 4 + r;
        float v = acc[j][s][r];
        unsigned short h = f2bf(v);
        sm.a.Ah[lm][col] = h;
        sm.a.Al[lm][col] = f2bf(v - bf2f(h));
      }
  }
  __syncthreads();
  if (f.mode == 1) {                              // l=2: only rel1 k|v survives pruning
    proj_kv(sm.a.Ah, sm.a.Al, t, m0, f.CWF_n + (size_t)2 * 32768,
            f.CB_n + 2 * HID, f.CB_n + 3 * HID, f.Pkv1);
    return;
  }
  if (y == 0)      proj_q (sm.a.Ah, sm.a.Al, t, m0, f.WqF_n, f.bq_n0, f.Pq);
  else if (y == 1) proj_kv(sm.a.Ah, sm.a.Al, t, m0, f.CWF_n, f.CB_n, f.CB_n + HID, f.Pkv0);
  else             proj_kv(sm.a.Ah, sm.a.Al, t, m0, f.CWF_n + (size_t)2 * 32768,
                           f.CB_n + 2 * HID, f.CB_n + 3 * HID, f.Pkv1);
}

// ================= JK attention + node/graph MLPs =============================================
struct TailW {
  const float *win, *bin, *wout, *bout;
  const float *nw0, *nb0, *nw1, *nb1, *nw2, *nb2, *nw3, *nb3, *nw4, *nb4, *nw5, *nb5, *nw6, *nb6;
  const float *gw0, *gb0, *gw1, *gb1;
};

__launch_bounds__(128)
__global__ void k_final(const float* __restrict__ outsv, TailW tw, float* __restrict__ outp) {
  __shared__ float xs[4][HID], qq[4][HID], kk[4][HID], vv[4][HID], oo[4][HID];
  __shared__ float att[NH][4][4];
  __shared__ float hb[HID], tb[64];
  int b = blockIdx.x, t = threadIdx.x;
  for (int l = 0; l < 4; ++l) xs[l][t] = outsv[(size_t)(l * NV + b) * HID + t];
  __syncthreads();
  for (int l = 0; l < 4; ++l) {
    float sq = tw.bin[t], sk = tw.bin[t + 128], sv = tw.bin[t + 256];
    const float* wq = tw.win + (size_t)t * HID;
    const float* wk = tw.win + (size_t)(t + 128) * HID;
    const float* wv = tw.win + (size_t)(t + 256) * HID;
    for (int c = 0; c < HID; ++c) {
      float x = xs[l][c];
      sq += x * wq[c]; sk += x * wk[c]; sv += x * wv[c];
    }
    qq[l][t] = sq; kk[l][t] = sk; vv[l][t] = sv;
  }
  __syncthreads();
  {
    int h = t >> 4, ql = (t >> 2) & 3, kl = t & 3;
    float s = 0.f;
    #pragma unroll
    for (int d = 0; d < DH; ++d) s += qq[ql][h * DH + d] * kk[kl][h * DH + d];
    att[h][ql][kl] = s * SCALE;
  }
  __syncthreads();
  if (t < 32) {
    int h = t >> 2, ql = t & 3;
    float m = att[h][ql][0];
    for (int k2 = 1; k2 < 4; ++k2) m = fmaxf(m, att[h][ql][k2]);
    float e[4], s = 0.f;
    for (int k2 = 0; k2 < 4; ++k2) { e[k2] = __expf(att[h][ql][k2] - m); s += e[k2]; }
    for (int k2 = 0; k2 < 4; ++k2) att[h][ql][k2] = e[k2] / s;
  }
  __syncthreads();
  {
    int h = t >> 4;
    #pragma unroll
    for (int ql = 0; ql < 4; ++ql) {
      float s = 0.f;
      #pragma unroll
      for (int kl = 0; kl < 4; ++kl) s += att[h][ql][kl] * vv[kl][t];
      oo[ql][t] = s;
    }
  }
  __syncthreads();
  {
    float s = 0.f;
    const float* wr = tw.wout + (size_t)t * HID;
    for (int l = 0; l < 4; ++l) {
      float ss = tw.bout[t];
      for (int c = 0; c < HID; ++c) ss += oo[l][c] * wr[c];
      s += ss;
    }
    hb[t] = s;
  }
  __syncthreads();
  if (t < 64) { float s = tw.nb0[t]; const float* wr = tw.nw0 + t * 128; for (int c = 0; c < 128; ++c) s += hb[c] * wr[c]; tb[t] = gelu_f(s); }
  __syncthreads();
  if (t < 32) { float s = tw.nb1[t]; const float* wr = tw.nw1 + t * 64;  for (int c = 0; c < 64;  ++c) s += tb[c] * wr[c]; hb[t] = gelu_f(s); }
  __syncthreads();
  if (t < 16) { float s = tw.nb2[t]; const float* wr = tw.nw2 + t * 32;  for (int c = 0; c < 32;  ++c) s += hb[c] * wr[c]; tb[t] = gelu_f(s); }
  __syncthreads();
  if (t < 8)  { float s = tw.nb3[t]; const float* wr = tw.nw3 + t * 16;  for (int c = 0; c < 16;  ++c) s += tb[c] * wr[c]; hb[t] = gelu_f(s); }
  __syncthreads();
  if (t < 4)  { float s = tw.nb4[t]; const float* wr = tw.nw4 + t * 8;   for (int c = 0; c < 8;   ++c) s += hb[c] * wr[c]; tb[t] = gelu_f(s); }
  __syncthreads();
  if (t < 2)  { float s = tw.nb5[t]; const float* wr = tw.nw5 + t * 4;   for (int c = 0; c < 4;   ++c) s += tb[c] * wr[c]; hb[t] = gelu_f(s); }
  __syncthreads();
  if (t == 0) {
    float s = hb[0] * tw.nw6[0] + hb[1] * tw.nw6[1] + tw.nb6[0];
    float g0 = gelu_f(s * tw.gw0[0] + tw.gb0[0]);
    float g1 = gelu_f(s * tw.gw0[1] + tw.gb0[1]);
    outp[b] = g0 * tw.gw1[0] + g1 * tw.gw1[1] + tw.gb1[0];
  }
}

// ================= host =======================================================================
extern "C" void kernel_launch(void* const* d_in, const int* in_sizes, int n_in,
                              void* d_out, int out_size, void* d_ws, size_t ws_size,
                              hipStream_t stream) {
  const float* x_op = (const float*)d_in[0];
  const float* x_v  = (const float*)d_in[1];
  const int*   ei0  = (const int*)d_in[2];
  const int*   ei1  = (const int*)d_in[3];
  const float* Wk   = (const float*)d_in[4];
  const float* Wq   = (const float*)d_in[5];
  const float* Wv   = (const float*)d_in[6];
  const float* Wa   = (const float*)d_in[7];
  const float* bk   = (const float*)d_in[8];
  const float* bq   = (const float*)d_in[9];
  const float* bv   = (const float*)d_in[10];
  const float* ba   = (const float*)d_in[11];
  const float* skip = (const float*)d_in[12];
  const float* a_rel = (const float*)d_in[13];
  const float* m_rel = (const float*)d_in[14];
  const float* p_rel = (const float*)d_in[15];
  (void)in_sizes; (void)n_in; (void)out_size; (void)ws_size;

  char* wsp = (char*)d_ws;
  size_t off = 0;
  auto alloc = [&](size_t bytes) -> void* {
    void* p = wsp + off;
    off += (bytes + 255) & ~(size_t)255;
    return p;
  };
  float* Pq    = (float*)alloc((size_t)NN * HID * 4);
  unsigned int* Pkv0 = (unsigned int*)alloc((size_t)NN * HID * 4);  // fp16 k|v packed per dword
  unsigned int* Pkv1 = (unsigned int*)alloc((size_t)NN * HID * 4);
  float* xop   = (float*)alloc((size_t)NN * HID * 4);
  float* agg   = (float*)alloc((size_t)NN * HID * 4);
  float* CW    = (float*)alloc((size_t)16 * HID * HID * 4);
  float* CB    = (float*)alloc((size_t)16 * HID * 4);
  unsigned short* FW = (unsigned short*)alloc((size_t)24 * 32768 * 2);  // 1.57 MB frag weights
  float* xv    = (float*)alloc((size_t)NV * HID * 4);
  float* qv    = (float*)alloc((size_t)NV * HID * 4);
  float* outsv = (float*)alloc((size_t)NL * NV * HID * 4);
  float* part  = (float*)alloc((size_t)NV * 32 * 192 * 4);
  int* cnt0    = (int*)alloc((size_t)NN * 4);
  int* colB0   = (int*)alloc((size_t)NN * CAP0 * 4);   // 8 MB fixed-cap buckets
  int* cnt1    = (int*)alloc((size_t)NV * 4);
  int* colB1   = (int*)alloc((size_t)NV * CAP1 * 4);

  hipMemsetAsync(cnt0, 0, (size_t)NN * 4, stream);
  hipMemsetAsync(cnt1, 0, (size_t)NV * 4, stream);

  k_setup<<<16, 256, 0, stream>>>(Wk, Wv, bk, bv, a_rel, m_rel, p_rel, CW, CB);
  k_frag<<<24, 256, 0, stream>>>(CW, Wq, Wa, FW);

  PreArgs pa;
  pa.src0 = ei0; pa.dst0 = ei0 + E0E;
  pa.src1 = ei1; pa.dst1 = ei1 + NN;
  pa.cnt0 = cnt0; pa.cnt1 = cnt1; pa.colB0 = colB0; pa.colB1 = colB1;
  pa.x_op = x_op; pa.FW = FW; pa.bq = bq; pa.CB = CB;
  pa.Pq = Pq; pa.Pkv0 = Pkv0; pa.Pkv1 = Pkv1;
  pa.x_v = x_v; pa.Wq1 = Wq + (size_t)1 * HID * HID; pa.bq1 = bq + HID; pa.qv = qv;
  k_pre<<<E0E / 1024 + NN / 1024 + 3 * (NN / 64) + NV, 256, 0, stream>>>(pa);

  for (int l = 0; l < NL; ++l) {
    int e0b = (l < NL - 1) ? NN / 4 : 0;       // l=3 edge0 aggregation is DEAD (x_op unused)
    k_edges<<<e0b + NV * 8, 256, 0, stream>>>(Pq, Pkv0, Pkv1, cnt0, colB0, agg,
                                              qv, cnt1, colB1, part, e0b);
    PArgs f;
    f.agg = agg;
    f.WaF_l = FW + (size_t)(20 + l) * 32768;
    f.ba_l0 = ba + (l * 2 + 0) * HID;
    f.skip_l0 = skip + l * 2 + 0;
    f.xold = (l == 0) ? x_op : xop;
    f.xop = xop;
    f.part = part;
    f.Wa_l1 = Wa + (size_t)(l * 2 + 1) * HID * HID;
    f.ba_l1 = ba + (l * 2 + 1) * HID;
    f.skip_l1 = skip + l * 2 + 1;
    f.xvold = (l == 0) ? x_v : xv;
    f.xv = xv;
    f.outsv_l = outsv + (size_t)l * NV * HID;
    f.qv = qv;
    int ln = (l + 1) & 3;
    f.Wq_n1 = Wq + (size_t)(ln * 2 + 1) * HID * HID;
    f.bq_n1 = bq + (ln * 2 + 1) * HID;
    f.do_qv = (l < NL - 1) ? 1 : 0;
    f.WqF_n = FW + (size_t)(16 + ln) * 32768;
    f.CWF_n = FW + (size_t)(ln * 4) * 32768;
    f.bq_n0 = bq + (ln * 2 + 0) * HID;
    f.CB_n  = CB + ln * 4 * HID;
    f.Pq = Pq; f.Pkv0 = Pkv0; f.Pkv1 = Pkv1;
    if (l < 2) {
      f.mode = 0;
      k_post<<<dim3(NN / 64 + NV, 3), 256, 0, stream>>>(f);
    } else if (l == 2) {
      f.mode = 1;
      k_post<<<NN / 64 + NV, 256, 0, stream>>>(f);
    } else {
      f.mode = 2;
      k_post<<<NV, 256, 0, stream>>>(f);
    }
  }

  TailW tw;
  tw.win  = (const float*)d_in[16]; tw.bin  = (const float*)d_in[17];
  tw.wout = (const float*)d_in[18]; tw.bout = (const float*)d_in[19];
  tw.nw0 = (const float*)d_in[20]; tw.nb0 = (const float*)d_in[21];
  tw.nw1 = (const float*)d_in[22]; tw.nb1 = (const float*)d_in[23];
  tw.nw2 = (const float*)d_in[24]; tw.nb2 = (const float*)d_in[25];
  tw.nw3 = (const float*)d_in[26]; tw.nb3 = (const float*)d_in[27];
  tw.nw4 = (const float*)d_in[28]; tw.nb4 = (const float*)d_in[29];
  tw.nw5 = (const float*)d_in[30]; tw.nb5 = (const float*)d_in[31];
  tw.nw6 = (const float*)d_in[32]; tw.nb6 = (const float*)d_in[33];
  tw.gw0 = (const float*)d_in[34]; tw.gb0 = (const float*)d_in[35];
  tw.gw1 = (const float*)d_in[36]; tw.gb1 = (const float*)d_in[37];
  k_final<<<NV, 128, 0, stream>>>(outsv, tw, (float*)d_out);
}